// Round 8
// baseline (329.199 us; speedup 1.0000x reference)
//
// R8: VALU diet. R7 post-mortem: VALUBusy 56% is now the top pipe; LDS-ratio
// ceiling (27.8% model == 28.6% measured MfmaUtil) and 2-wave/SIMD reg cap
// block tile changes. Cuts: (1) epilogue -> u32 packed candidates
// (24-bit fmono score + 8-bit in-chunk id; chunk id implicit in blockIdx.x),
// branch-free min/max top-2 network, single-shuffle merges, u32 bufs;
// (2) staging -> 6 per-lane pointers incremented 64B/k-step (2A+4B per wave,
// same verified lane->LDS map); (3) loss reduce 1 block -> 64 blocks.
// Margin audit: quant step ~0.016 + fp16 err ~0.03 << MU=0.25; exact rerank
// restores true argmin when captured.
#include <hip/hip_runtime.h>
#include <stdint.h>

#define N_TOK   16384
#define DIM     512
#define K_CODES 8192
#define BM      128
#define BN      256
#define BK      32
#define NCHUNK  32
#define MU      0.25f    // rerank margin; fp16+quant score err << MU

typedef __attribute__((ext_vector_type(8))) _Float16 f16x8;
typedef __attribute__((ext_vector_type(4))) _Float16 f16x4;
typedef __attribute__((ext_vector_type(4))) float f32x4;

__device__ __forceinline__ unsigned int fmono(float f) {
  unsigned int b = __float_as_uint(f);
  unsigned int mask = ((int)b < 0) ? 0xFFFFFFFFu : 0x80000000u;
  return b ^ mask;
}
__device__ __forceinline__ float finv(unsigned int m) {
  return (m & 0x80000000u) ? __uint_as_float(m ^ 0x80000000u)
                           : __uint_as_float(~m);
}
__device__ __forceinline__ void async16(const void* gptr, void* lptr) {
  __builtin_amdgcn_global_load_lds(
      (const __attribute__((address_space(1))) unsigned int*)gptr,
      (__attribute__((address_space(3))) unsigned int*)lptr,
      16, 0, 0);
}
__device__ __forceinline__ unsigned int umin32(unsigned int a, unsigned int b) {
  return a < b ? a : b;
}
__device__ __forceinline__ unsigned int umax32(unsigned int a, unsigned int b) {
  return a < b ? b : a;
}

// ---------------- cast X: fp32 -> fp16 ----------------
__global__ __launch_bounds__(256) void castx_kernel(
    const float* __restrict__ in, _Float16* __restrict__ out) {
  const int gid = blockIdx.x * 256 + threadIdx.x;   // one float4 each
  const float4 v = ((const float4*)in)[gid];
  f16x4 h;
  h.x = (_Float16)v.x; h.y = (_Float16)v.y;
  h.z = (_Float16)v.z; h.w = (_Float16)v.w;
  *(f16x4*)(out + (size_t)gid * 4) = h;
}

// ---------------- enorm (fp64-exact) + cast E: fp32 -> fp16 ----------------
__global__ __launch_bounds__(256) void enorm_cast_kernel(
    const float* __restrict__ ew, float* __restrict__ enorm,
    _Float16* __restrict__ E16) {
  const int lane = threadIdx.x & 63;
  const int wid  = threadIdx.x >> 6;
  const int row  = blockIdx.x * 4 + wid;
  const float4 v0 = *(const float4*)(ew + (size_t)row * DIM + lane * 8);
  const float4 v1 = *(const float4*)(ew + (size_t)row * DIM + lane * 8 + 4);
  const float f[8] = {v0.x, v0.y, v0.z, v0.w, v1.x, v1.y, v1.z, v1.w};
  f16x8 h;
  double s = 0.0;
#pragma unroll
  for (int k = 0; k < 8; ++k) {
    s = fma((double)f[k], (double)f[k], s);
    h[k] = (_Float16)f[k];
  }
  *(f16x8*)(E16 + (size_t)row * DIM + lane * 8) = h;
#pragma unroll
  for (int off = 32; off > 0; off >>= 1) s += __shfl_down(s, off, 64);
  if (lane == 0) enorm[row] = (float)s;
}

// ---------------- main: fp16 K=512 GEMM + per-chunk top-2 ----------------
// Block tile 128x256 (one chunk), 4 waves, wave tile 64x128, 2-phase dbuf.
// Candidates packed u32: (fmono(score) & 0xFFFFFF00) | code8 (code within
// chunk; chunk == blockIdx.x). Top-2 per (i,r) via sorted min/max network,
// xor1 single-shuffle merge, 16 u32x2 slots/row (disjoint wave halves),
// scan -> u32 buf1/buf2.
__global__ __launch_bounds__(256) void gemm_top2_kernel(
    const _Float16* __restrict__ X16,   // N x 512
    const _Float16* __restrict__ E16,   // K x 512
    const float* __restrict__ enorm,
    unsigned int* __restrict__ buf1,    // [token][32] packed top-1
    unsigned int* __restrict__ buf2) {  // [token][32] packed top-2
  __shared__ __align__(16) union {
    _Float16 buf[2][12288];           // per phase: A bytes 0..8K, B 8K..24K
    unsigned int mg[BM][16][2];       // 16KB merge
  } sh;

  const int tid  = threadIdx.x;
  const int lane = tid & 63;
  const int wid  = tid >> 6;
  const int quad = lane >> 4;
  const int l15  = lane & 15;

  const int row0  = blockIdx.y * BM;
  const int nbase = blockIdx.x * BN;

  const int wm = (wid >> 1) * 64;    // 0 or 64  (rows)
  const int wn = (wid & 1) * 128;    // 0 or 128 (codes)

  // staging: 24 issues of 1KB (16 rows x 64B). Per wave: A issues wid*2+q
  // (q<2), B issues wid*4+q (q<4) -- covers A 0..7, B 0..15. lane -> row
  // lane>>2, phys slot lane&3, fetched chunk (lane&3)^((lane>>3)&3)
  // (baseline-verified map; dest base is wave-uniform as required).
  const int srow   = lane >> 2;
  const int schunk = (lane & 3) ^ ((lane >> 3) & 3);

  const int ia0 = wid * 2, ib0 = wid * 4;
  const _Float16* pA0 = X16 + (size_t)(row0 + ia0 * 16 + srow) * DIM + schunk * 8;
  const _Float16* pA1 = pA0 + (size_t)16 * DIM;
  const _Float16* pB0 = E16 + (size_t)(nbase + ib0 * 16 + srow) * DIM + schunk * 8;
  const _Float16* pB1 = pB0 + (size_t)16 * DIM;
  const _Float16* pB2 = pB1 + (size_t)16 * DIM;
  const _Float16* pB3 = pB2 + (size_t)16 * DIM;

  auto STAGE = [&](int p) {
    char* base = (char*)(&sh.buf[p][0]);
    async16(pA0, base + ia0 * 1024);
    async16(pA1, base + ia0 * 1024 + 1024);
    async16(pB0, base + 8192 + ib0 * 1024);
    async16(pB1, base + 8192 + ib0 * 1024 + 1024);
    async16(pB2, base + 8192 + ib0 * 1024 + 2048);
    async16(pB3, base + 8192 + ib0 * 1024 + 3072);
    pA0 += BK; pA1 += BK; pB0 += BK; pB1 += BK; pB2 += BK; pB3 += BK;
  };

  f32x4 acc[4][8];
#pragma unroll
  for (int i = 0; i < 4; ++i)
#pragma unroll
    for (int j = 0; j < 8; ++j) acc[i][j] = (f32x4){0.f, 0.f, 0.f, 0.f};

  STAGE(0);
  __syncthreads();

  for (int ks = 0; ks < DIM / BK; ++ks) {
    const int p = ks & 1;
    if (ks < DIM / BK - 1) STAGE(p ^ 1);

    const char* baseA = (const char*)(&sh.buf[p][0]);
    const char* baseB = baseA + 8192;
    f16x8 a[4];
#pragma unroll
    for (int i = 0; i < 4; ++i) {
      const int ra = wm + i * 16 + l15;
      a[i] = *(const f16x8*)(baseA + ra * 64 + ((quad ^ ((ra >> 1) & 3)) * 16));
    }
    // two j-halves of 4: limits concurrent b-frag liveness to 32 VGPR;
    // each half's ds_reads hide under its 16 MFMAs.
#pragma unroll
    for (int jh = 0; jh < 2; ++jh) {
      f16x8 b[4];
#pragma unroll
      for (int jj = 0; jj < 4; ++jj) {
        const int rb = wn + (jh * 4 + jj) * 16 + l15;
        b[jj] = *(const f16x8*)(baseB + rb * 64 + ((quad ^ ((rb >> 1) & 3)) * 16));
      }
#pragma unroll
      for (int i = 0; i < 4; ++i)
#pragma unroll
        for (int jj = 0; jj < 4; ++jj)
          acc[i][jh * 4 + jj] = __builtin_amdgcn_mfma_f32_16x16x32_f16(
              a[i], b[jj], acc[i][jh * 4 + jj], 0, 0, 0);
    }
    __syncthreads();   // drains this iter's STAGE (vmcnt) + all ds_reads
  }

  // ---- epilogue (atomic-free, branch-free u32 network) ----
  float en8[8];
#pragma unroll
  for (int j = 0; j < 8; ++j) en8[j] = enorm[nbase + wn + j * 16 + l15];
  const unsigned int cb = (unsigned int)(wn + l15);   // in-chunk code base, 8-bit

#pragma unroll
  for (int i = 0; i < 4; ++i) {
    const int mrow = wm + i * 16 + quad * 4;
#pragma unroll
    for (int r = 0; r < 4; ++r) {
      unsigned int c[8];
#pragma unroll
      for (int j = 0; j < 8; ++j) {
        const float v = fmaf(-2.f, acc[i][j][r], en8[j]);
        c[j] = (fmono(v) & 0xFFFFFF00u) | (cb + j * 16);
      }
      // sorted-pair leaves
      const unsigned int l0 = umin32(c[0], c[1]), h0 = umax32(c[0], c[1]);
      const unsigned int l1 = umin32(c[2], c[3]), h1 = umax32(c[2], c[3]);
      const unsigned int l2 = umin32(c[4], c[5]), h2 = umax32(c[4], c[5]);
      const unsigned int l3 = umin32(c[6], c[7]), h3 = umax32(c[6], c[7]);
      // merge pairs (sorted-pair merge over disjoint sets)
      const unsigned int L0 = umin32(l0, l1);
      const unsigned int S0 = umin32(umax32(l0, l1), umin32(h0, h1));
      const unsigned int L1 = umin32(l2, l3);
      const unsigned int S1 = umin32(umax32(l2, l3), umin32(h2, h3));
      unsigned int p1 = umin32(L0, L1);
      unsigned int p2 = umin32(umax32(L0, L1), umin32(S0, S1));
      // xor1 cross-lane merge (single 32-bit shuffles)
      {
        const unsigned int q1 = (unsigned int)__shfl_xor((int)p1, 1, 64);
        const unsigned int q2 = (unsigned int)__shfl_xor((int)p2, 1, 64);
        const unsigned int hi = umax32(p1, q1);
        p1 = umin32(p1, q1);
        p2 = umin32(hi, umin32(p2, q2));
      }
      if (!(lane & 1)) {
        const int row = mrow + r;
        uint2 w; w.x = p1; w.y = p2;
        // 16 writers/row across 2 waves -> 16 distinct slots (disjoint
        // halves by wid&1; ^(row&7) touches bits 0-2 only, bijective).
        *(uint2*)&sh.mg[row][((wid & 1) * 8 + (l15 >> 1)) ^ (row & 7)][0] = w;
      }
    }
  }
  __syncthreads();

  if (tid < BM) {
    unsigned int g1 = 0xFFFFFFFFu, g2 = 0xFFFFFFFFu;
#pragma unroll
    for (int s = 0; s < 16; ++s) {
      const uint2 v = *(const uint2*)&sh.mg[tid][s ^ (tid & 7)][0];
      const unsigned int lo = umin32(v.x, g1);
      const unsigned int hi = umax32(v.x, g1);
      g1 = lo;
      g2 = umin32(hi, umin32(v.y, g2));
    }
    buf1[(size_t)(row0 + tid) * NCHUNK + blockIdx.x] = g1;
    buf2[(size_t)(row0 + tid) * NCHUNK + blockIdx.x] = g2;
  }
}

// ---------------- fused: exact fp64 rerank + gather + loss ----------------
// One wave per token. Candidate u32 = (mono24 | code8); global code id =
// chunk*256 + code8, chunk = slot index. finv of the floored mono is a
// score lower bound -- uniform across candidates, margin MU absorbs quant.
__global__ __launch_bounds__(256) void rerank_gather_loss_kernel(
    const float* __restrict__ xs, const float* __restrict__ ew,
    const unsigned int* __restrict__ buf1,
    const unsigned int* __restrict__ buf2,
    float* __restrict__ out, float* __restrict__ loss_part) {
  const int lane = threadIdx.x & 63;
  const int wv = threadIdx.x >> 6;
  const int tok = blockIdx.x * 4 + wv;
  const unsigned int p = (lane < 32)
      ? buf1[(size_t)tok * NCHUNK + lane]
      : buf2[(size_t)tok * NCHUNK + (lane - 32)];
  const float S = finv(p & 0xFFFFFF00u);
  float m = S;
#pragma unroll
  for (int off = 32; off > 0; off >>= 1) m = fminf(m, __shfl_xor(m, off, 64));
  unsigned long long mask = __ballot(S < m + MU);

  const float4 x0 = *(const float4*)(xs + (size_t)tok * DIM + lane * 8);
  const float4 x1 = *(const float4*)(xs + (size_t)tok * DIM + lane * 8 + 4);
  const double xd[8] = {x0.x, x0.y, x0.z, x0.w, x1.x, x1.y, x1.z, x1.w};

  double best = __builtin_inf();
  unsigned int besti = 0xFFFFFFFFu;
  while (mask) {
    const int src = __ffsll(mask) - 1;
    mask &= mask - 1;
    const unsigned int pp = (unsigned int)__shfl((int)p, src, 64);
    const unsigned int ci = (unsigned int)((src & 31) << 8) | (pp & 0xFFu);
    const float4 e0 = *(const float4*)(ew + (size_t)ci * DIM + lane * 8);
    const float4 e1 = *(const float4*)(ew + (size_t)ci * DIM + lane * 8 + 4);
    const double ed[8] = {e0.x, e0.y, e0.z, e0.w, e1.x, e1.y, e1.z, e1.w};
    double s = 0.0;
#pragma unroll
    for (int k = 0; k < 8; ++k) {
      const double d = xd[k] - ed[k];
      s = fma(d, d, s);
    }
#pragma unroll
    for (int off = 32; off > 0; off >>= 1) s += __shfl_xor(s, off, 64);
    if (s < best || (s == best && ci < besti)) { best = s; besti = ci; }
  }

  // gather winner row + loss partial (all lanes agree on besti)
  const float4 e0 = *(const float4*)(ew + (size_t)besti * DIM + lane * 8);
  const float4 e1 = *(const float4*)(ew + (size_t)besti * DIM + lane * 8 + 4);
  *(float4*)(out + (size_t)tok * DIM + lane * 8) = e0;
  *(float4*)(out + (size_t)tok * DIM + lane * 8 + 4) = e1;
  const float ef[8] = {e0.x, e0.y, e0.z, e0.w, e1.x, e1.y, e1.z, e1.w};
  const float xf[8] = {x0.x, x0.y, x0.z, x0.w, x1.x, x1.y, x1.z, x1.w};
  float ls = 0.f;
#pragma unroll
  for (int k = 0; k < 8; ++k) {
    const float d = ef[k] - xf[k];
    ls = fmaf(d, d, ls);
  }
#pragma unroll
  for (int off = 32; off > 0; off >>= 1) ls += __shfl_xor(ls, off, 64);
  if (lane == 0) loss_part[tok] = ls;
}

// loss partial reduce: 64 blocks x 256 -> one atomic per block.
__global__ __launch_bounds__(256) void loss_reduce_part(
    const float* __restrict__ part, float* __restrict__ loss_acc) {
  const int t = threadIdx.x;
  float s = part[blockIdx.x * 256 + t];
#pragma unroll
  for (int off = 32; off > 0; off >>= 1) s += __shfl_down(s, off, 64);
  __shared__ float ws4[4];
  if ((t & 63) == 0) ws4[t >> 6] = s;
  __syncthreads();
  if (t == 0) atomicAdd(loss_acc, ws4[0] + ws4[1] + ws4[2] + ws4[3]);
}

__global__ void loss_finalize(const float* __restrict__ loss_acc,
                              float* __restrict__ out, int out_size) {
  if (threadIdx.x == 0 && blockIdx.x == 0)
    out[out_size - 1] = *loss_acc * 1.25f / (float)((size_t)N_TOK * DIM);
}

// ---------------- fallback: exact fp64 brute (known-passing) ----------------
#define TT 16
#define CT 16
#define KH 256
#define XPAD 516
#define EPAD 260
__global__ __launch_bounds__(256) void brute_argmin_kernel(
    const float* __restrict__ xs, const float* __restrict__ ew,
    unsigned int* __restrict__ g_idx) {
  __shared__ __align__(16) float Xs[TT * XPAD];
  __shared__ __align__(16) float Es[CT * EPAD];
  __shared__ double cand_v[256];
  __shared__ unsigned int cand_i[256];
  const int t = threadIdx.x;
  const int tok0 = blockIdx.x * TT;
#pragma unroll
  for (int i = 0; i < 32; ++i) {
    const int idx = i * 256 + t;
    const int row = idx >> 9, col = idx & 511;
    Xs[row * XPAD + col] = xs[(size_t)(tok0 + row) * DIM + col];
  }
  const int tt = t >> 4;
  const int cl = t & 15;
  double bv = __builtin_inf();
  unsigned int bi = 0u;
  for (int c0 = 0; c0 < K_CODES; c0 += CT) {
    double s0 = 0.0, s1 = 0.0, s2 = 0.0, s3 = 0.0;
#pragma unroll
    for (int h = 0; h < 2; ++h) {
      __syncthreads();
#pragma unroll
      for (int i = 0; i < 16; ++i) {
        const int idx = i * 256 + t;
        const int row = idx >> 8, col = idx & 255;
        Es[row * EPAD + col] = ew[(size_t)(c0 + row) * DIM + h * KH + col];
      }
      __syncthreads();
      const float* __restrict__ xr = &Xs[tt * XPAD + h * KH];
      const float* __restrict__ er = &Es[cl * EPAD];
#pragma unroll 8
      for (int d = 0; d < KH; d += 4) {
        const float4 xf = *(const float4*)(xr + d);
        const float4 ef = *(const float4*)(er + d);
        const double a0 = (double)xf.x - (double)ef.x;
        const double a1 = (double)xf.y - (double)ef.y;
        const double a2 = (double)xf.z - (double)ef.z;
        const double a3 = (double)xf.w - (double)ef.w;
        s0 = fma(a0, a0, s0); s1 = fma(a1, a1, s1);
        s2 = fma(a2, a2, s2); s3 = fma(a3, a3, s3);
      }
    }
    const double s = (s0 + s1) + (s2 + s3);
    if (s < bv) { bv = s; bi = (unsigned int)(c0 + cl); }
  }
  cand_v[t] = bv; cand_i[t] = bi;
  __syncthreads();
  if (t < TT) {
    double mv = __builtin_inf();
    unsigned int mi = 0xFFFFFFFFu;
#pragma unroll
    for (int j = 0; j < 16; ++j) {
      const double v = cand_v[t * 16 + j];
      const unsigned int i = cand_i[t * 16 + j];
      if (v < mv || (v == mv && i < mi)) { mv = v; mi = i; }
    }
    g_idx[tok0 + t] = mi;
  }
}

__global__ __launch_bounds__(256) void gather_loss_kernel(
    const float* __restrict__ xs, const float* __restrict__ ew,
    const unsigned int* __restrict__ g_idx,
    float* __restrict__ out, float* __restrict__ loss_acc) {
  const int row = blockIdx.x;
  const int t = threadIdx.x;
  const unsigned int idx = g_idx[row];
  const float2 ev = ((const float2*)(ew + (size_t)idx * DIM))[t];
  const float2 xv = ((const float2*)(xs + (size_t)row * DIM))[t];
  ((float2*)(out + (size_t)row * DIM))[t] = ev;
  const float d0 = ev.x - xv.x;
  const float d1 = ev.y - xv.y;
  float s = fmaf(d0, d0, d1 * d1);
#pragma unroll
  for (int off = 32; off > 0; off >>= 1) s += __shfl_down(s, off, 64);
  __shared__ float wsum[4];
  if ((t & 63) == 0) wsum[t >> 6] = s;
  __syncthreads();
  if (t == 0) atomicAdd(loss_acc, wsum[0] + wsum[1] + wsum[2] + wsum[3]);
}

// ---------------- launch ----------------
extern "C" void kernel_launch(void* const* d_in, const int* in_sizes, int n_in,
                              void* d_out, int out_size, void* d_ws, size_t ws_size,
                              hipStream_t stream) {
  const float* xs = (const float*)d_in[0];
  const float* ew = (const float*)d_in[1];
  if (n_in >= 2 && in_sizes[0] == K_CODES * DIM && in_sizes[1] == N_TOK * DIM) {
    const float* tmp = xs; xs = ew; ew = tmp;
  }
  float* out = (float*)d_out;

  char* w = (char*)d_ws;
  _Float16* X16 = (_Float16*)(w);                                   // 16 MB
  _Float16* E16 = (_Float16*)(w + 16777216);                        // 8 MB
  float* enorm = (float*)(w + 25165824);                            // 32 KB
  unsigned int* buf1 = (unsigned int*)(w + 25198592);               // 2 MB
  unsigned int* buf2 = (unsigned int*)(w + 27295744);               // 2 MB
  float* loss_acc = (float*)(w + 29392896);
  const size_t NEED = 29392960;

  // loss partials overlay the X16 region (dead after gemm; rerank is its
  // stream-ordered writer). Zero extra workspace.
  float* loss_part = (float*)(w);

  if (ws_size < NEED) {   // fallback: proven exact path
    unsigned int* fg_idx = (unsigned int*)d_ws;
    float* floss = (float*)((char*)d_ws + (size_t)N_TOK * 4);
    hipMemsetAsync(floss, 0, 4, stream);
    brute_argmin_kernel<<<N_TOK / TT, 256, 0, stream>>>(xs, ew, fg_idx);
    gather_loss_kernel<<<N_TOK, 256, 0, stream>>>(xs, ew, fg_idx, out, floss);
    loss_finalize<<<1, 64, 0, stream>>>(floss, out, out_size);
    return;
  }

  hipMemsetAsync(loss_acc, 0, 4, stream);

  castx_kernel<<<N_TOK * DIM / 4 / 256, 256, 0, stream>>>(xs, X16);
  enorm_cast_kernel<<<K_CODES / 4, 256, 0, stream>>>(ew, enorm, E16);

  dim3 g2(K_CODES / BN, N_TOK / BM);   // 32 x 128
  gemm_top2_kernel<<<g2, 256, 0, stream>>>(X16, E16, enorm, buf1, buf2);

  rerank_gather_loss_kernel<<<N_TOK / 4, 256, 0, stream>>>(xs, ew, buf1, buf2,
                                                           out, loss_part);
  loss_reduce_part<<<N_TOK / 256, 256, 0, stream>>>(loss_part, loss_acc);
  loss_finalize<<<1, 64, 0, stream>>>(loss_acc, out, out_size);
}

// Round 9
// 288.015 us; speedup vs baseline: 1.1430x; 1.1430x over previous
//
// R9: fix R8's register cliff. R8 post-mortem: u32 epilogue worked (VALUBusy
// 56->22.5) but 6 persistent staging pointers pushed VGPR 120->136; 136+128acc
// = 264 > 256 -> 1 wave/SIMD (occupancy 21->11%), net regression. Fix:
// (a) 2 persistent base pointers (pA,pB), 4 derived addrs with const offsets
// at issue time (+8 VALU/k-step, -8 persistent VGPR); (b) launch_bounds(256,2)
// pins allocator at <=256 regs incl. acc (8-reg nudge, not R4's 44-reg squeeze).
#include <hip/hip_runtime.h>
#include <stdint.h>

#define N_TOK   16384
#define DIM     512
#define K_CODES 8192
#define BM      128
#define BN      256
#define BK      32
#define NCHUNK  32
#define MU      0.25f    // rerank margin; fp16+quant score err << MU

typedef __attribute__((ext_vector_type(8))) _Float16 f16x8;
typedef __attribute__((ext_vector_type(4))) _Float16 f16x4;
typedef __attribute__((ext_vector_type(4))) float f32x4;

__device__ __forceinline__ unsigned int fmono(float f) {
  unsigned int b = __float_as_uint(f);
  unsigned int mask = ((int)b < 0) ? 0xFFFFFFFFu : 0x80000000u;
  return b ^ mask;
}
__device__ __forceinline__ float finv(unsigned int m) {
  return (m & 0x80000000u) ? __uint_as_float(m ^ 0x80000000u)
                           : __uint_as_float(~m);
}
__device__ __forceinline__ void async16(const void* gptr, void* lptr) {
  __builtin_amdgcn_global_load_lds(
      (const __attribute__((address_space(1))) unsigned int*)gptr,
      (__attribute__((address_space(3))) unsigned int*)lptr,
      16, 0, 0);
}
__device__ __forceinline__ unsigned int umin32(unsigned int a, unsigned int b) {
  return a < b ? a : b;
}
__device__ __forceinline__ unsigned int umax32(unsigned int a, unsigned int b) {
  return a < b ? b : a;
}

// ---------------- cast X: fp32 -> fp16 ----------------
__global__ __launch_bounds__(256) void castx_kernel(
    const float* __restrict__ in, _Float16* __restrict__ out) {
  const int gid = blockIdx.x * 256 + threadIdx.x;   // one float4 each
  const float4 v = ((const float4*)in)[gid];
  f16x4 h;
  h.x = (_Float16)v.x; h.y = (_Float16)v.y;
  h.z = (_Float16)v.z; h.w = (_Float16)v.w;
  *(f16x4*)(out + (size_t)gid * 4) = h;
}

// ---------------- enorm (fp64-exact) + cast E: fp32 -> fp16 ----------------
__global__ __launch_bounds__(256) void enorm_cast_kernel(
    const float* __restrict__ ew, float* __restrict__ enorm,
    _Float16* __restrict__ E16) {
  const int lane = threadIdx.x & 63;
  const int wid  = threadIdx.x >> 6;
  const int row  = blockIdx.x * 4 + wid;
  const float4 v0 = *(const float4*)(ew + (size_t)row * DIM + lane * 8);
  const float4 v1 = *(const float4*)(ew + (size_t)row * DIM + lane * 8 + 4);
  const float f[8] = {v0.x, v0.y, v0.z, v0.w, v1.x, v1.y, v1.z, v1.w};
  f16x8 h;
  double s = 0.0;
#pragma unroll
  for (int k = 0; k < 8; ++k) {
    s = fma((double)f[k], (double)f[k], s);
    h[k] = (_Float16)f[k];
  }
  *(f16x8*)(E16 + (size_t)row * DIM + lane * 8) = h;
#pragma unroll
  for (int off = 32; off > 0; off >>= 1) s += __shfl_down(s, off, 64);
  if (lane == 0) enorm[row] = (float)s;
}

// ---------------- main: fp16 K=512 GEMM + per-chunk top-2 ----------------
// Block tile 128x256 (one chunk), 4 waves, wave tile 64x128, 2-phase dbuf.
// Candidates packed u32: (fmono(score) & 0xFFFFFF00) | code8 (code within
// chunk; chunk == blockIdx.x). Top-2 per (i,r) via sorted min/max network,
// xor1 single-shuffle merge, 16 u32x2 slots/row (disjoint wave halves),
// scan -> u32 buf1/buf2.
__global__ __launch_bounds__(256, 2) void gemm_top2_kernel(
    const _Float16* __restrict__ X16,   // N x 512
    const _Float16* __restrict__ E16,   // K x 512
    const float* __restrict__ enorm,
    unsigned int* __restrict__ buf1,    // [token][32] packed top-1
    unsigned int* __restrict__ buf2) {  // [token][32] packed top-2
  __shared__ __align__(16) union {
    _Float16 buf[2][12288];           // per phase: A bytes 0..8K, B 8K..24K
    unsigned int mg[BM][16][2];       // 16KB merge
  } sh;

  const int tid  = threadIdx.x;
  const int lane = tid & 63;
  const int wid  = tid >> 6;
  const int quad = lane >> 4;
  const int l15  = lane & 15;

  const int row0  = blockIdx.y * BM;
  const int nbase = blockIdx.x * BN;

  const int wm = (wid >> 1) * 64;    // 0 or 64  (rows)
  const int wn = (wid & 1) * 128;    // 0 or 128 (codes)

  // staging: 24 issues of 1KB (16 rows x 64B). Per wave: A issues wid*2+q
  // (q<2), B issues wid*4+q (q<4). lane -> row lane>>2, phys slot lane&3,
  // fetched chunk (lane&3)^((lane>>3)&3) (baseline-verified map; LDS dest
  // base wave-uniform as required). Only TWO persistent pointers; the other
  // 4 addresses are derived with compile-time-constant byte offsets.
  const int srow   = lane >> 2;
  const int schunk = (lane & 3) ^ ((lane >> 3) & 3);

  const int ia0 = wid * 2, ib0 = wid * 4;
  const _Float16* pA = X16 + (size_t)(row0 + ia0 * 16 + srow) * DIM + schunk * 8;
  const _Float16* pB = E16 + (size_t)(nbase + ib0 * 16 + srow) * DIM + schunk * 8;

  auto STAGE = [&](int p) {
    char* base = (char*)(&sh.buf[p][0]);
    async16(pA,            base + ia0 * 1024);
    async16(pA + 16 * DIM, base + ia0 * 1024 + 1024);
    async16(pB,            base + 8192 + ib0 * 1024);
    async16(pB + 16 * DIM, base + 8192 + ib0 * 1024 + 1024);
    async16(pB + 32 * DIM, base + 8192 + ib0 * 1024 + 2048);
    async16(pB + 48 * DIM, base + 8192 + ib0 * 1024 + 3072);
    pA += BK; pB += BK;
  };

  f32x4 acc[4][8];
#pragma unroll
  for (int i = 0; i < 4; ++i)
#pragma unroll
    for (int j = 0; j < 8; ++j) acc[i][j] = (f32x4){0.f, 0.f, 0.f, 0.f};

  STAGE(0);
  __syncthreads();

  for (int ks = 0; ks < DIM / BK; ++ks) {
    const int p = ks & 1;
    if (ks < DIM / BK - 1) STAGE(p ^ 1);

    const char* baseA = (const char*)(&sh.buf[p][0]);
    const char* baseB = baseA + 8192;
    f16x8 a[4];
#pragma unroll
    for (int i = 0; i < 4; ++i) {
      const int ra = wm + i * 16 + l15;
      a[i] = *(const f16x8*)(baseA + ra * 64 + ((quad ^ ((ra >> 1) & 3)) * 16));
    }
    // two j-halves of 4: limits concurrent b-frag liveness to 32 VGPR;
    // each half's ds_reads hide under its 16 MFMAs.
#pragma unroll
    for (int jh = 0; jh < 2; ++jh) {
      f16x8 b[4];
#pragma unroll
      for (int jj = 0; jj < 4; ++jj) {
        const int rb = wn + (jh * 4 + jj) * 16 + l15;
        b[jj] = *(const f16x8*)(baseB + rb * 64 + ((quad ^ ((rb >> 1) & 3)) * 16));
      }
#pragma unroll
      for (int i = 0; i < 4; ++i)
#pragma unroll
        for (int jj = 0; jj < 4; ++jj)
          acc[i][jh * 4 + jj] = __builtin_amdgcn_mfma_f32_16x16x32_f16(
              a[i], b[jj], acc[i][jh * 4 + jj], 0, 0, 0);
    }
    __syncthreads();   // drains this iter's STAGE (vmcnt) + all ds_reads
  }

  // ---- epilogue (atomic-free, branch-free u32 network) ----
  float en8[8];
#pragma unroll
  for (int j = 0; j < 8; ++j) en8[j] = enorm[nbase + wn + j * 16 + l15];
  const unsigned int cb = (unsigned int)(wn + l15);   // in-chunk code base, 8-bit

#pragma unroll
  for (int i = 0; i < 4; ++i) {
    const int mrow = wm + i * 16 + quad * 4;
#pragma unroll
    for (int r = 0; r < 4; ++r) {
      unsigned int c[8];
#pragma unroll
      for (int j = 0; j < 8; ++j) {
        const float v = fmaf(-2.f, acc[i][j][r], en8[j]);
        c[j] = (fmono(v) & 0xFFFFFF00u) | (cb + j * 16);
      }
      // sorted-pair leaves
      const unsigned int l0 = umin32(c[0], c[1]), h0 = umax32(c[0], c[1]);
      const unsigned int l1 = umin32(c[2], c[3]), h1 = umax32(c[2], c[3]);
      const unsigned int l2 = umin32(c[4], c[5]), h2 = umax32(c[4], c[5]);
      const unsigned int l3 = umin32(c[6], c[7]), h3 = umax32(c[6], c[7]);
      // merge pairs (sorted-pair merge over disjoint sets)
      const unsigned int L0 = umin32(l0, l1);
      const unsigned int S0 = umin32(umax32(l0, l1), umin32(h0, h1));
      const unsigned int L1 = umin32(l2, l3);
      const unsigned int S1 = umin32(umax32(l2, l3), umin32(h2, h3));
      unsigned int p1 = umin32(L0, L1);
      unsigned int p2 = umin32(umax32(L0, L1), umin32(S0, S1));
      // xor1 cross-lane merge (single 32-bit shuffles)
      {
        const unsigned int q1 = (unsigned int)__shfl_xor((int)p1, 1, 64);
        const unsigned int q2 = (unsigned int)__shfl_xor((int)p2, 1, 64);
        const unsigned int hi = umax32(p1, q1);
        p1 = umin32(p1, q1);
        p2 = umin32(hi, umin32(p2, q2));
      }
      if (!(lane & 1)) {
        const int row = mrow + r;
        uint2 w; w.x = p1; w.y = p2;
        // 16 writers/row across 2 waves -> 16 distinct slots (disjoint
        // halves by wid&1; ^(row&7) touches bits 0-2 only, bijective).
        *(uint2*)&sh.mg[row][((wid & 1) * 8 + (l15 >> 1)) ^ (row & 7)][0] = w;
      }
    }
  }
  __syncthreads();

  if (tid < BM) {
    unsigned int g1 = 0xFFFFFFFFu, g2 = 0xFFFFFFFFu;
#pragma unroll
    for (int s = 0; s < 16; ++s) {
      const uint2 v = *(const uint2*)&sh.mg[tid][s ^ (tid & 7)][0];
      const unsigned int lo = umin32(v.x, g1);
      const unsigned int hi = umax32(v.x, g1);
      g1 = lo;
      g2 = umin32(hi, umin32(v.y, g2));
    }
    buf1[(size_t)(row0 + tid) * NCHUNK + blockIdx.x] = g1;
    buf2[(size_t)(row0 + tid) * NCHUNK + blockIdx.x] = g2;
  }
}

// ---------------- fused: exact fp64 rerank + gather + loss ----------------
// One wave per token. Candidate u32 = (mono24 | code8); global code id =
// chunk*256 + code8, chunk = slot index. finv of the floored mono is a
// score lower bound -- uniform across candidates, margin MU absorbs quant.
__global__ __launch_bounds__(256) void rerank_gather_loss_kernel(
    const float* __restrict__ xs, const float* __restrict__ ew,
    const unsigned int* __restrict__ buf1,
    const unsigned int* __restrict__ buf2,
    float* __restrict__ out, float* __restrict__ loss_part) {
  const int lane = threadIdx.x & 63;
  const int wv = threadIdx.x >> 6;
  const int tok = blockIdx.x * 4 + wv;
  const unsigned int p = (lane < 32)
      ? buf1[(size_t)tok * NCHUNK + lane]
      : buf2[(size_t)tok * NCHUNK + (lane - 32)];
  const float S = finv(p & 0xFFFFFF00u);
  float m = S;
#pragma unroll
  for (int off = 32; off > 0; off >>= 1) m = fminf(m, __shfl_xor(m, off, 64));
  unsigned long long mask = __ballot(S < m + MU);

  const float4 x0 = *(const float4*)(xs + (size_t)tok * DIM + lane * 8);
  const float4 x1 = *(const float4*)(xs + (size_t)tok * DIM + lane * 8 + 4);
  const double xd[8] = {x0.x, x0.y, x0.z, x0.w, x1.x, x1.y, x1.z, x1.w};

  double best = __builtin_inf();
  unsigned int besti = 0xFFFFFFFFu;
  while (mask) {
    const int src = __ffsll(mask) - 1;
    mask &= mask - 1;
    const unsigned int pp = (unsigned int)__shfl((int)p, src, 64);
    const unsigned int ci = (unsigned int)((src & 31) << 8) | (pp & 0xFFu);
    const float4 e0 = *(const float4*)(ew + (size_t)ci * DIM + lane * 8);
    const float4 e1 = *(const float4*)(ew + (size_t)ci * DIM + lane * 8 + 4);
    const double ed[8] = {e0.x, e0.y, e0.z, e0.w, e1.x, e1.y, e1.z, e1.w};
    double s = 0.0;
#pragma unroll
    for (int k = 0; k < 8; ++k) {
      const double d = xd[k] - ed[k];
      s = fma(d, d, s);
    }
#pragma unroll
    for (int off = 32; off > 0; off >>= 1) s += __shfl_xor(s, off, 64);
    if (s < best || (s == best && ci < besti)) { best = s; besti = ci; }
  }

  // gather winner row + loss partial (all lanes agree on besti)
  const float4 e0 = *(const float4*)(ew + (size_t)besti * DIM + lane * 8);
  const float4 e1 = *(const float4*)(ew + (size_t)besti * DIM + lane * 8 + 4);
  *(float4*)(out + (size_t)tok * DIM + lane * 8) = e0;
  *(float4*)(out + (size_t)tok * DIM + lane * 8 + 4) = e1;
  const float ef[8] = {e0.x, e0.y, e0.z, e0.w, e1.x, e1.y, e1.z, e1.w};
  const float xf[8] = {x0.x, x0.y, x0.z, x0.w, x1.x, x1.y, x1.z, x1.w};
  float ls = 0.f;
#pragma unroll
  for (int k = 0; k < 8; ++k) {
    const float d = ef[k] - xf[k];
    ls = fmaf(d, d, ls);
  }
#pragma unroll
  for (int off = 32; off > 0; off >>= 1) ls += __shfl_xor(ls, off, 64);
  if (lane == 0) loss_part[tok] = ls;
}

// loss partial reduce: 64 blocks x 256 -> one atomic per block.
__global__ __launch_bounds__(256) void loss_reduce_part(
    const float* __restrict__ part, float* __restrict__ loss_acc) {
  const int t = threadIdx.x;
  float s = part[blockIdx.x * 256 + t];
#pragma unroll
  for (int off = 32; off > 0; off >>= 1) s += __shfl_down(s, off, 64);
  __shared__ float ws4[4];
  if ((t & 63) == 0) ws4[t >> 6] = s;
  __syncthreads();
  if (t == 0) atomicAdd(loss_acc, ws4[0] + ws4[1] + ws4[2] + ws4[3]);
}

__global__ void loss_finalize(const float* __restrict__ loss_acc,
                              float* __restrict__ out, int out_size) {
  if (threadIdx.x == 0 && blockIdx.x == 0)
    out[out_size - 1] = *loss_acc * 1.25f / (float)((size_t)N_TOK * DIM);
}

// ---------------- fallback: exact fp64 brute (known-passing) ----------------
#define TT 16
#define CT 16
#define KH 256
#define XPAD 516
#define EPAD 260
__global__ __launch_bounds__(256) void brute_argmin_kernel(
    const float* __restrict__ xs, const float* __restrict__ ew,
    unsigned int* __restrict__ g_idx) {
  __shared__ __align__(16) float Xs[TT * XPAD];
  __shared__ __align__(16) float Es[CT * EPAD];
  __shared__ double cand_v[256];
  __shared__ unsigned int cand_i[256];
  const int t = threadIdx.x;
  const int tok0 = blockIdx.x * TT;
#pragma unroll
  for (int i = 0; i < 32; ++i) {
    const int idx = i * 256 + t;
    const int row = idx >> 9, col = idx & 511;
    Xs[row * XPAD + col] = xs[(size_t)(tok0 + row) * DIM + col];
  }
  const int tt = t >> 4;
  const int cl = t & 15;
  double bv = __builtin_inf();
  unsigned int bi = 0u;
  for (int c0 = 0; c0 < K_CODES; c0 += CT) {
    double s0 = 0.0, s1 = 0.0, s2 = 0.0, s3 = 0.0;
#pragma unroll
    for (int h = 0; h < 2; ++h) {
      __syncthreads();
#pragma unroll
      for (int i = 0; i < 16; ++i) {
        const int idx = i * 256 + t;
        const int row = idx >> 8, col = idx & 255;
        Es[row * EPAD + col] = ew[(size_t)(c0 + row) * DIM + h * KH + col];
      }
      __syncthreads();
      const float* __restrict__ xr = &Xs[tt * XPAD + h * KH];
      const float* __restrict__ er = &Es[cl * EPAD];
#pragma unroll 8
      for (int d = 0; d < KH; d += 4) {
        const float4 xf = *(const float4*)(xr + d);
        const float4 ef = *(const float4*)(er + d);
        const double a0 = (double)xf.x - (double)ef.x;
        const double a1 = (double)xf.y - (double)ef.y;
        const double a2 = (double)xf.z - (double)ef.z;
        const double a3 = (double)xf.w - (double)ef.w;
        s0 = fma(a0, a0, s0); s1 = fma(a1, a1, s1);
        s2 = fma(a2, a2, s2); s3 = fma(a3, a3, s3);
      }
    }
    const double s = (s0 + s1) + (s2 + s3);
    if (s < bv) { bv = s; bi = (unsigned int)(c0 + cl); }
  }
  cand_v[t] = bv; cand_i[t] = bi;
  __syncthreads();
  if (t < TT) {
    double mv = __builtin_inf();
    unsigned int mi = 0xFFFFFFFFu;
#pragma unroll
    for (int j = 0; j < 16; ++j) {
      const double v = cand_v[t * 16 + j];
      const unsigned int i = cand_i[t * 16 + j];
      if (v < mv || (v == mv && i < mi)) { mv = v; mi = i; }
    }
    g_idx[tok0 + t] = mi;
  }
}

__global__ __launch_bounds__(256) void gather_loss_kernel(
    const float* __restrict__ xs, const float* __restrict__ ew,
    const unsigned int* __restrict__ g_idx,
    float* __restrict__ out, float* __restrict__ loss_acc) {
  const int row = blockIdx.x;
  const int t = threadIdx.x;
  const unsigned int idx = g_idx[row];
  const float2 ev = ((const float2*)(ew + (size_t)idx * DIM))[t];
  const float2 xv = ((const float2*)(xs + (size_t)row * DIM))[t];
  ((float2*)(out + (size_t)row * DIM))[t] = ev;
  const float d0 = ev.x - xv.x;
  const float d1 = ev.y - xv.y;
  float s = fmaf(d0, d0, d1 * d1);
#pragma unroll
  for (int off = 32; off > 0; off >>= 1) s += __shfl_down(s, off, 64);
  __shared__ float wsum[4];
  if ((t & 63) == 0) wsum[t >> 6] = s;
  __syncthreads();
  if (t == 0) atomicAdd(loss_acc, wsum[0] + wsum[1] + wsum[2] + wsum[3]);
}

// ---------------- launch ----------------
extern "C" void kernel_launch(void* const* d_in, const int* in_sizes, int n_in,
                              void* d_out, int out_size, void* d_ws, size_t ws_size,
                              hipStream_t stream) {
  const float* xs = (const float*)d_in[0];
  const float* ew = (const float*)d_in[1];
  if (n_in >= 2 && in_sizes[0] == K_CODES * DIM && in_sizes[1] == N_TOK * DIM) {
    const float* tmp = xs; xs = ew; ew = tmp;
  }
  float* out = (float*)d_out;

  char* w = (char*)d_ws;
  _Float16* X16 = (_Float16*)(w);                                   // 16 MB
  _Float16* E16 = (_Float16*)(w + 16777216);                        // 8 MB
  float* enorm = (float*)(w + 25165824);                            // 32 KB
  unsigned int* buf1 = (unsigned int*)(w + 25198592);               // 2 MB
  unsigned int* buf2 = (unsigned int*)(w + 27295744);               // 2 MB
  float* loss_acc = (float*)(w + 29392896);
  const size_t NEED = 29392960;

  // loss partials overlay the X16 region (dead after gemm; rerank is its
  // stream-ordered writer). Zero extra workspace.
  float* loss_part = (float*)(w);

  if (ws_size < NEED) {   // fallback: proven exact path
    unsigned int* fg_idx = (unsigned int*)d_ws;
    float* floss = (float*)((char*)d_ws + (size_t)N_TOK * 4);
    hipMemsetAsync(floss, 0, 4, stream);
    brute_argmin_kernel<<<N_TOK / TT, 256, 0, stream>>>(xs, ew, fg_idx);
    gather_loss_kernel<<<N_TOK, 256, 0, stream>>>(xs, ew, fg_idx, out, floss);
    loss_finalize<<<1, 64, 0, stream>>>(floss, out, out_size);
    return;
  }

  hipMemsetAsync(loss_acc, 0, 4, stream);

  castx_kernel<<<N_TOK * DIM / 4 / 256, 256, 0, stream>>>(xs, X16);
  enorm_cast_kernel<<<K_CODES / 4, 256, 0, stream>>>(ew, enorm, E16);

  dim3 g2(K_CODES / BN, N_TOK / BM);   // 32 x 128
  gemm_top2_kernel<<<g2, 256, 0, stream>>>(X16, E16, enorm, buf1, buf2);

  rerank_gather_loss_kernel<<<N_TOK / 4, 256, 0, stream>>>(xs, ew, buf1, buf2,
                                                           out, loss_part);
  loss_reduce_part<<<N_TOK / 256, 256, 0, stream>>>(loss_part, loss_acc);
  loss_finalize<<<1, 64, 0, stream>>>(loss_acc, out, out_size);
}

// Round 10
// 266.880 us; speedup vs baseline: 1.2335x; 1.0792x over previous
//
// R10: 3-deep counted-vmcnt pipeline (T3/T4-min port). R9 post-mortem: all
// predictions hit (VGPR 120, 2 w/SIMD, gemm 171us). Residual: MfmaUtil 37 +
// VALU 32 -> ~30% stall = __syncthreads vmcnt(0)-drain waiting on just-issued
// next-tile loads (L3-resident operands, ~500cy, only ~300cy cover). Fix:
// triple-buffer (72KB, still 2 blocks/CU), s_waitcnt vmcnt(6) completes the
// oldest tile only, raw s_barrier (no drain), STAGE(ks+2) after barrier.
// Loads get ~2 k-steps of cover. Peeled last iter uses vmcnt(0).
#include <hip/hip_runtime.h>
#include <stdint.h>

#define N_TOK   16384
#define DIM     512
#define K_CODES 8192
#define BM      128
#define BN      256
#define BK      32
#define NK      (DIM / BK)
#define NCHUNK  32
#define MU      0.25f    // rerank margin; fp16+quant score err << MU

typedef __attribute__((ext_vector_type(8))) _Float16 f16x8;
typedef __attribute__((ext_vector_type(4))) _Float16 f16x4;
typedef __attribute__((ext_vector_type(4))) float f32x4;

__device__ __forceinline__ unsigned int fmono(float f) {
  unsigned int b = __float_as_uint(f);
  unsigned int mask = ((int)b < 0) ? 0xFFFFFFFFu : 0x80000000u;
  return b ^ mask;
}
__device__ __forceinline__ float finv(unsigned int m) {
  return (m & 0x80000000u) ? __uint_as_float(m ^ 0x80000000u)
                           : __uint_as_float(~m);
}
__device__ __forceinline__ void async16(const void* gptr, void* lptr) {
  __builtin_amdgcn_global_load_lds(
      (const __attribute__((address_space(1))) unsigned int*)gptr,
      (__attribute__((address_space(3))) unsigned int*)lptr,
      16, 0, 0);
}
__device__ __forceinline__ unsigned int umin32(unsigned int a, unsigned int b) {
  return a < b ? a : b;
}
__device__ __forceinline__ unsigned int umax32(unsigned int a, unsigned int b) {
  return a < b ? b : a;
}

// ---------------- cast X: fp32 -> fp16 ----------------
__global__ __launch_bounds__(256) void castx_kernel(
    const float* __restrict__ in, _Float16* __restrict__ out) {
  const int gid = blockIdx.x * 256 + threadIdx.x;   // one float4 each
  const float4 v = ((const float4*)in)[gid];
  f16x4 h;
  h.x = (_Float16)v.x; h.y = (_Float16)v.y;
  h.z = (_Float16)v.z; h.w = (_Float16)v.w;
  *(f16x4*)(out + (size_t)gid * 4) = h;
}

// ---------------- enorm (fp64-exact) + cast E: fp32 -> fp16 ----------------
__global__ __launch_bounds__(256) void enorm_cast_kernel(
    const float* __restrict__ ew, float* __restrict__ enorm,
    _Float16* __restrict__ E16) {
  const int lane = threadIdx.x & 63;
  const int wid  = threadIdx.x >> 6;
  const int row  = blockIdx.x * 4 + wid;
  const float4 v0 = *(const float4*)(ew + (size_t)row * DIM + lane * 8);
  const float4 v1 = *(const float4*)(ew + (size_t)row * DIM + lane * 8 + 4);
  const float f[8] = {v0.x, v0.y, v0.z, v0.w, v1.x, v1.y, v1.z, v1.w};
  f16x8 h;
  double s = 0.0;
#pragma unroll
  for (int k = 0; k < 8; ++k) {
    s = fma((double)f[k], (double)f[k], s);
    h[k] = (_Float16)f[k];
  }
  *(f16x8*)(E16 + (size_t)row * DIM + lane * 8) = h;
#pragma unroll
  for (int off = 32; off > 0; off >>= 1) s += __shfl_down(s, off, 64);
  if (lane == 0) enorm[row] = (float)s;
}

// ---------------- main: fp16 K=512 GEMM + per-chunk top-2 ----------------
// Block tile 128x256 (one chunk), 4 waves, wave tile 64x128, 3-deep pipeline.
// Candidates packed u32: (fmono(score) & 0xFFFFFF00) | code8; chunk id is
// blockIdx.x. Top-2 via sorted min/max network, xor1 single-shuffle merge,
// 16 u32x2 slots/row (disjoint wave halves), scan -> u32 buf1/buf2.
__global__ __launch_bounds__(256, 2) void gemm_top2_kernel(
    const _Float16* __restrict__ X16,   // N x 512
    const _Float16* __restrict__ E16,   // K x 512
    const float* __restrict__ enorm,
    unsigned int* __restrict__ buf1,    // [token][32] packed top-1
    unsigned int* __restrict__ buf2) {  // [token][32] packed top-2
  __shared__ __align__(16) union {
    _Float16 buf[3][12288];           // per phase: A bytes 0..8K, B 8K..24K
    unsigned int mg[BM][16][2];       // 16KB merge (aliases buf[0])
  } sh;

  const int tid  = threadIdx.x;
  const int lane = tid & 63;
  const int wid  = tid >> 6;
  const int quad = lane >> 4;
  const int l15  = lane & 15;

  const int row0  = blockIdx.y * BM;
  const int nbase = blockIdx.x * BN;

  const int wm = (wid >> 1) * 64;    // 0 or 64  (rows)
  const int wn = (wid & 1) * 128;    // 0 or 128 (codes)

  // staging: 24 issues of 1KB (16 rows x 64B). Per wave: A issues wid*2+q
  // (q<2), B issues wid*4+q (q<4). lane -> row lane>>2, phys slot lane&3,
  // fetched chunk (lane&3)^((lane>>3)&3) (baseline-verified map; LDS dest
  // base wave-uniform as required). Two persistent pointers, derived offsets.
  const int srow   = lane >> 2;
  const int schunk = (lane & 3) ^ ((lane >> 3) & 3);

  const int ia0 = wid * 2, ib0 = wid * 4;
  const _Float16* pA = X16 + (size_t)(row0 + ia0 * 16 + srow) * DIM + schunk * 8;
  const _Float16* pB = E16 + (size_t)(nbase + ib0 * 16 + srow) * DIM + schunk * 8;

  auto STAGE = [&](int p) {
    char* base = (char*)(&sh.buf[p][0]);
    async16(pA,            base + ia0 * 1024);
    async16(pA + 16 * DIM, base + ia0 * 1024 + 1024);
    async16(pB,            base + 8192 + ib0 * 1024);
    async16(pB + 16 * DIM, base + 8192 + ib0 * 1024 + 1024);
    async16(pB + 32 * DIM, base + 8192 + ib0 * 1024 + 2048);
    async16(pB + 48 * DIM, base + 8192 + ib0 * 1024 + 3072);
    pA += BK; pB += BK;
  };

  f32x4 acc[4][8];
#pragma unroll
  for (int i = 0; i < 4; ++i)
#pragma unroll
    for (int j = 0; j < 8; ++j) acc[i][j] = (f32x4){0.f, 0.f, 0.f, 0.f};

  auto COMPUTE = [&](int p) {
    const char* baseA = (const char*)(&sh.buf[p][0]);
    const char* baseB = baseA + 8192;
    f16x8 a[4];
#pragma unroll
    for (int i = 0; i < 4; ++i) {
      const int ra = wm + i * 16 + l15;
      a[i] = *(const f16x8*)(baseA + ra * 64 + ((quad ^ ((ra >> 1) & 3)) * 16));
    }
    // two j-halves of 4: limits concurrent b-frag liveness to 32 VGPR.
#pragma unroll
    for (int jh = 0; jh < 2; ++jh) {
      f16x8 b[4];
#pragma unroll
      for (int jj = 0; jj < 4; ++jj) {
        const int rb = wn + (jh * 4 + jj) * 16 + l15;
        b[jj] = *(const f16x8*)(baseB + rb * 64 + ((quad ^ ((rb >> 1) & 3)) * 16));
      }
#pragma unroll
      for (int i = 0; i < 4; ++i)
#pragma unroll
        for (int jj = 0; jj < 4; ++jj)
          acc[i][jh * 4 + jj] = __builtin_amdgcn_mfma_f32_16x16x32_f16(
              a[i], b[jj], acc[i][jh * 4 + jj], 0, 0, 0);
    }
  };

  // ---- 3-deep pipeline ----
  // Invariant at iter ks top: own outstanding loads = tile ks (6) + tile
  // ks+1 (6). vmcnt(6) completes the OLDEST 6 (tile ks, FIFO). s_barrier:
  // all waves' tile-ks loads landed AND all waves finished compute(ks-1)
  // (arrival is after it in program order) -> STAGE(ks+2) may overwrite
  // buf[(ks-1)%3]. The asm "memory" clobber fences IR-level reordering;
  // sched_barrier(0) pins the scheduler (rule #18).
  STAGE(0); STAGE(1);
  int pc = 0;
  for (int ks = 0; ks < NK - 1; ++ks) {
    asm volatile("s_waitcnt vmcnt(6)" ::: "memory");
    __builtin_amdgcn_sched_barrier(0);
    __builtin_amdgcn_s_barrier();
    __builtin_amdgcn_sched_barrier(0);
    if (ks + 2 < NK) {
      const int pn = (pc + 2 >= 3) ? pc - 1 : pc + 2;
      STAGE(pn);
    }
    COMPUTE(pc);
    pc = (pc + 1 >= 3) ? 0 : pc + 1;
  }
  asm volatile("s_waitcnt vmcnt(0)" ::: "memory");
  __builtin_amdgcn_sched_barrier(0);
  __builtin_amdgcn_s_barrier();
  __builtin_amdgcn_sched_barrier(0);
  COMPUTE(pc);
  __syncthreads();   // all waves done reading buf before mg (union) writes

  // ---- epilogue (atomic-free, branch-free u32 network) ----
  float en8[8];
#pragma unroll
  for (int j = 0; j < 8; ++j) en8[j] = enorm[nbase + wn + j * 16 + l15];
  const unsigned int cb = (unsigned int)(wn + l15);   // in-chunk code base, 8-bit

#pragma unroll
  for (int i = 0; i < 4; ++i) {
    const int mrow = wm + i * 16 + quad * 4;
#pragma unroll
    for (int r = 0; r < 4; ++r) {
      unsigned int c[8];
#pragma unroll
      for (int j = 0; j < 8; ++j) {
        const float v = fmaf(-2.f, acc[i][j][r], en8[j]);
        c[j] = (fmono(v) & 0xFFFFFF00u) | (cb + j * 16);
      }
      // sorted-pair leaves
      const unsigned int l0 = umin32(c[0], c[1]), h0 = umax32(c[0], c[1]);
      const unsigned int l1 = umin32(c[2], c[3]), h1 = umax32(c[2], c[3]);
      const unsigned int l2 = umin32(c[4], c[5]), h2 = umax32(c[4], c[5]);
      const unsigned int l3 = umin32(c[6], c[7]), h3 = umax32(c[6], c[7]);
      // merge pairs (sorted-pair merge over disjoint sets)
      const unsigned int L0 = umin32(l0, l1);
      const unsigned int S0 = umin32(umax32(l0, l1), umin32(h0, h1));
      const unsigned int L1 = umin32(l2, l3);
      const unsigned int S1 = umin32(umax32(l2, l3), umin32(h2, h3));
      unsigned int p1 = umin32(L0, L1);
      unsigned int p2 = umin32(umax32(L0, L1), umin32(S0, S1));
      // xor1 cross-lane merge (single 32-bit shuffles)
      {
        const unsigned int q1 = (unsigned int)__shfl_xor((int)p1, 1, 64);
        const unsigned int q2 = (unsigned int)__shfl_xor((int)p2, 1, 64);
        const unsigned int hi = umax32(p1, q1);
        p1 = umin32(p1, q1);
        p2 = umin32(hi, umin32(p2, q2));
      }
      if (!(lane & 1)) {
        const int row = mrow + r;
        uint2 w; w.x = p1; w.y = p2;
        // 16 writers/row across 2 waves -> 16 distinct slots (disjoint
        // halves by wid&1; ^(row&7) touches bits 0-2 only, bijective).
        *(uint2*)&sh.mg[row][((wid & 1) * 8 + (l15 >> 1)) ^ (row & 7)][0] = w;
      }
    }
  }
  __syncthreads();

  if (tid < BM) {
    unsigned int g1 = 0xFFFFFFFFu, g2 = 0xFFFFFFFFu;
#pragma unroll
    for (int s = 0; s < 16; ++s) {
      const uint2 v = *(const uint2*)&sh.mg[tid][s ^ (tid & 7)][0];
      const unsigned int lo = umin32(v.x, g1);
      const unsigned int hi = umax32(v.x, g1);
      g1 = lo;
      g2 = umin32(hi, umin32(v.y, g2));
    }
    buf1[(size_t)(row0 + tid) * NCHUNK + blockIdx.x] = g1;
    buf2[(size_t)(row0 + tid) * NCHUNK + blockIdx.x] = g2;
  }
}

// ---------------- fused: exact fp64 rerank + gather + loss ----------------
// One wave per token. Candidate u32 = (mono24 | code8); global code id =
// chunk*256 + code8, chunk = slot index. finv of the floored mono is a
// score lower bound -- uniform across candidates, margin MU absorbs quant.
__global__ __launch_bounds__(256) void rerank_gather_loss_kernel(
    const float* __restrict__ xs, const float* __restrict__ ew,
    const unsigned int* __restrict__ buf1,
    const unsigned int* __restrict__ buf2,
    float* __restrict__ out, float* __restrict__ loss_part) {
  const int lane = threadIdx.x & 63;
  const int wv = threadIdx.x >> 6;
  const int tok = blockIdx.x * 4 + wv;
  const unsigned int p = (lane < 32)
      ? buf1[(size_t)tok * NCHUNK + lane]
      : buf2[(size_t)tok * NCHUNK + (lane - 32)];
  const float S = finv(p & 0xFFFFFF00u);
  float m = S;
#pragma unroll
  for (int off = 32; off > 0; off >>= 1) m = fminf(m, __shfl_xor(m, off, 64));
  unsigned long long mask = __ballot(S < m + MU);

  const float4 x0 = *(const float4*)(xs + (size_t)tok * DIM + lane * 8);
  const float4 x1 = *(const float4*)(xs + (size_t)tok * DIM + lane * 8 + 4);
  const double xd[8] = {x0.x, x0.y, x0.z, x0.w, x1.x, x1.y, x1.z, x1.w};

  double best = __builtin_inf();
  unsigned int besti = 0xFFFFFFFFu;
  while (mask) {
    const int src = __ffsll(mask) - 1;
    mask &= mask - 1;
    const unsigned int pp = (unsigned int)__shfl((int)p, src, 64);
    const unsigned int ci = (unsigned int)((src & 31) << 8) | (pp & 0xFFu);
    const float4 e0 = *(const float4*)(ew + (size_t)ci * DIM + lane * 8);
    const float4 e1 = *(const float4*)(ew + (size_t)ci * DIM + lane * 8 + 4);
    const double ed[8] = {e0.x, e0.y, e0.z, e0.w, e1.x, e1.y, e1.z, e1.w};
    double s = 0.0;
#pragma unroll
    for (int k = 0; k < 8; ++k) {
      const double d = xd[k] - ed[k];
      s = fma(d, d, s);
    }
#pragma unroll
    for (int off = 32; off > 0; off >>= 1) s += __shfl_xor(s, off, 64);
    if (s < best || (s == best && ci < besti)) { best = s; besti = ci; }
  }

  // gather winner row + loss partial (all lanes agree on besti)
  const float4 e0 = *(const float4*)(ew + (size_t)besti * DIM + lane * 8);
  const float4 e1 = *(const float4*)(ew + (size_t)besti * DIM + lane * 8 + 4);
  *(float4*)(out + (size_t)tok * DIM + lane * 8) = e0;
  *(float4*)(out + (size_t)tok * DIM + lane * 8 + 4) = e1;
  const float ef[8] = {e0.x, e0.y, e0.z, e0.w, e1.x, e1.y, e1.z, e1.w};
  const float xf[8] = {x0.x, x0.y, x0.z, x0.w, x1.x, x1.y, x1.z, x1.w};
  float ls = 0.f;
#pragma unroll
  for (int k = 0; k < 8; ++k) {
    const float d = ef[k] - xf[k];
    ls = fmaf(d, d, ls);
  }
#pragma unroll
  for (int off = 32; off > 0; off >>= 1) ls += __shfl_xor(ls, off, 64);
  if (lane == 0) loss_part[tok] = ls;
}

// loss partial reduce: 64 blocks x 256 -> one atomic per block.
__global__ __launch_bounds__(256) void loss_reduce_part(
    const float* __restrict__ part, float* __restrict__ loss_acc) {
  const int t = threadIdx.x;
  float s = part[blockIdx.x * 256 + t];
#pragma unroll
  for (int off = 32; off > 0; off >>= 1) s += __shfl_down(s, off, 64);
  __shared__ float ws4[4];
  if ((t & 63) == 0) ws4[t >> 6] = s;
  __syncthreads();
  if (t == 0) atomicAdd(loss_acc, ws4[0] + ws4[1] + ws4[2] + ws4[3]);
}

__global__ void loss_finalize(const float* __restrict__ loss_acc,
                              float* __restrict__ out, int out_size) {
  if (threadIdx.x == 0 && blockIdx.x == 0)
    out[out_size - 1] = *loss_acc * 1.25f / (float)((size_t)N_TOK * DIM);
}

// ---------------- fallback: exact fp64 brute (known-passing) ----------------
#define TT 16
#define CT 16
#define KH 256
#define XPAD 516
#define EPAD 260
__global__ __launch_bounds__(256) void brute_argmin_kernel(
    const float* __restrict__ xs, const float* __restrict__ ew,
    unsigned int* __restrict__ g_idx) {
  __shared__ __align__(16) float Xs[TT * XPAD];
  __shared__ __align__(16) float Es[CT * EPAD];
  __shared__ double cand_v[256];
  __shared__ unsigned int cand_i[256];
  const int t = threadIdx.x;
  const int tok0 = blockIdx.x * TT;
#pragma unroll
  for (int i = 0; i < 32; ++i) {
    const int idx = i * 256 + t;
    const int row = idx >> 9, col = idx & 511;
    Xs[row * XPAD + col] = xs[(size_t)(tok0 + row) * DIM + col];
  }
  const int tt = t >> 4;
  const int cl = t & 15;
  double bv = __builtin_inf();
  unsigned int bi = 0u;
  for (int c0 = 0; c0 < K_CODES; c0 += CT) {
    double s0 = 0.0, s1 = 0.0, s2 = 0.0, s3 = 0.0;
#pragma unroll
    for (int h = 0; h < 2; ++h) {
      __syncthreads();
#pragma unroll
      for (int i = 0; i < 16; ++i) {
        const int idx = i * 256 + t;
        const int row = idx >> 8, col = idx & 255;
        Es[row * EPAD + col] = ew[(size_t)(c0 + row) * DIM + h * KH + col];
      }
      __syncthreads();
      const float* __restrict__ xr = &Xs[tt * XPAD + h * KH];
      const float* __restrict__ er = &Es[cl * EPAD];
#pragma unroll 8
      for (int d = 0; d < KH; d += 4) {
        const float4 xf = *(const float4*)(xr + d);
        const float4 ef = *(const float4*)(er + d);
        const double a0 = (double)xf.x - (double)ef.x;
        const double a1 = (double)xf.y - (double)ef.y;
        const double a2 = (double)xf.z - (double)ef.z;
        const double a3 = (double)xf.w - (double)ef.w;
        s0 = fma(a0, a0, s0); s1 = fma(a1, a1, s1);
        s2 = fma(a2, a2, s2); s3 = fma(a3, a3, s3);
      }
    }
    const double s = (s0 + s1) + (s2 + s3);
    if (s < bv) { bv = s; bi = (unsigned int)(c0 + cl); }
  }
  cand_v[t] = bv; cand_i[t] = bi;
  __syncthreads();
  if (t < TT) {
    double mv = __builtin_inf();
    unsigned int mi = 0xFFFFFFFFu;
#pragma unroll
    for (int j = 0; j < 16; ++j) {
      const double v = cand_v[t * 16 + j];
      const unsigned int i = cand_i[t * 16 + j];
      if (v < mv || (v == mv && i < mi)) { mv = v; mi = i; }
    }
    g_idx[tok0 + t] = mi;
  }
}

__global__ __launch_bounds__(256) void gather_loss_kernel(
    const float* __restrict__ xs, const float* __restrict__ ew,
    const unsigned int* __restrict__ g_idx,
    float* __restrict__ out, float* __restrict__ loss_acc) {
  const int row = blockIdx.x;
  const int t = threadIdx.x;
  const unsigned int idx = g_idx[row];
  const float2 ev = ((const float2*)(ew + (size_t)idx * DIM))[t];
  const float2 xv = ((const float2*)(xs + (size_t)row * DIM))[t];
  ((float2*)(out + (size_t)row * DIM))[t] = ev;
  const float d0 = ev.x - xv.x;
  const float d1 = ev.y - xv.y;
  float s = fmaf(d0, d0, d1 * d1);
#pragma unroll
  for (int off = 32; off > 0; off >>= 1) s += __shfl_down(s, off, 64);
  __shared__ float wsum[4];
  if ((t & 63) == 0) wsum[t >> 6] = s;
  __syncthreads();
  if (t == 0) atomicAdd(loss_acc, wsum[0] + wsum[1] + wsum[2] + wsum[3]);
}

// ---------------- launch ----------------
extern "C" void kernel_launch(void* const* d_in, const int* in_sizes, int n_in,
                              void* d_out, int out_size, void* d_ws, size_t ws_size,
                              hipStream_t stream) {
  const float* xs = (const float*)d_in[0];
  const float* ew = (const float*)d_in[1];
  if (n_in >= 2 && in_sizes[0] == K_CODES * DIM && in_sizes[1] == N_TOK * DIM) {
    const float* tmp = xs; xs = ew; ew = tmp;
  }
  float* out = (float*)d_out;

  char* w = (char*)d_ws;
  _Float16* X16 = (_Float16*)(w);                                   // 16 MB
  _Float16* E16 = (_Float16*)(w + 16777216);                        // 8 MB
  float* enorm = (float*)(w + 25165824);                            // 32 KB
  unsigned int* buf1 = (unsigned int*)(w + 25198592);               // 2 MB
  unsigned int* buf2 = (unsigned int*)(w + 27295744);               // 2 MB
  float* loss_acc = (float*)(w + 29392896);
  const size_t NEED = 29392960;

  // loss partials overlay the X16 region (dead after gemm; rerank is its
  // stream-ordered writer). Zero extra workspace.
  float* loss_part = (float*)(w);

  if (ws_size < NEED) {   // fallback: proven exact path
    unsigned int* fg_idx = (unsigned int*)d_ws;
    float* floss = (float*)((char*)d_ws + (size_t)N_TOK * 4);
    hipMemsetAsync(floss, 0, 4, stream);
    brute_argmin_kernel<<<N_TOK / TT, 256, 0, stream>>>(xs, ew, fg_idx);
    gather_loss_kernel<<<N_TOK, 256, 0, stream>>>(xs, ew, fg_idx, out, floss);
    loss_finalize<<<1, 64, 0, stream>>>(floss, out, out_size);
    return;
  }

  hipMemsetAsync(loss_acc, 0, 4, stream);

  castx_kernel<<<N_TOK * DIM / 4 / 256, 256, 0, stream>>>(xs, X16);
  enorm_cast_kernel<<<K_CODES / 4, 256, 0, stream>>>(ew, enorm, E16);

  dim3 g2(K_CODES / BN, N_TOK / BM);   // 32 x 128
  gemm_top2_kernel<<<g2, 256, 0, stream>>>(X16, E16, enorm, buf1, buf2);

  rerank_gather_loss_kernel<<<N_TOK / 4, 256, 0, stream>>>(xs, ew, buf1, buf2,
                                                           out, loss_part);
  loss_reduce_part<<<N_TOK / 256, 256, 0, stream>>>(loss_part, loss_acc);
  loss_finalize<<<1, 64, 0, stream>>>(loss_acc, out, out_size);
}

// Round 11
// 262.479 us; speedup vs baseline: 1.2542x; 1.0168x over previous
//
// R11: overlap polish. R10 post-mortem: 3-deep pipeline +9us (gemm 162,
// MfmaUtil 39.5); structural ceiling at this geometry ~81% -> gap is overlap,
// not pipe ratio (barrier-exit ds_read burst stalls all waves on lgkmcnt).
// (1) T5 setprio(1) around each 16-MFMA cluster (counted-vmcnt structure =
// the enabling prereq per m218); (2) ds_reads issued BEFORE STAGE so MFMA
// data enters LDS queue first, STAGE VMEM issues overlap MFMA block 1;
// (3) rerank: keep winner row in regs (kills one dependent gather RT).
#include <hip/hip_runtime.h>
#include <stdint.h>

#define N_TOK   16384
#define DIM     512
#define K_CODES 8192
#define BM      128
#define BN      256
#define BK      32
#define NK      (DIM / BK)
#define NCHUNK  32
#define MU      0.25f    // rerank margin; fp16+quant score err << MU

typedef __attribute__((ext_vector_type(8))) _Float16 f16x8;
typedef __attribute__((ext_vector_type(4))) _Float16 f16x4;
typedef __attribute__((ext_vector_type(4))) float f32x4;

__device__ __forceinline__ unsigned int fmono(float f) {
  unsigned int b = __float_as_uint(f);
  unsigned int mask = ((int)b < 0) ? 0xFFFFFFFFu : 0x80000000u;
  return b ^ mask;
}
__device__ __forceinline__ float finv(unsigned int m) {
  return (m & 0x80000000u) ? __uint_as_float(m ^ 0x80000000u)
                           : __uint_as_float(~m);
}
__device__ __forceinline__ void async16(const void* gptr, void* lptr) {
  __builtin_amdgcn_global_load_lds(
      (const __attribute__((address_space(1))) unsigned int*)gptr,
      (__attribute__((address_space(3))) unsigned int*)lptr,
      16, 0, 0);
}
__device__ __forceinline__ unsigned int umin32(unsigned int a, unsigned int b) {
  return a < b ? a : b;
}
__device__ __forceinline__ unsigned int umax32(unsigned int a, unsigned int b) {
  return a < b ? b : a;
}

// ---------------- cast X: fp32 -> fp16 ----------------
__global__ __launch_bounds__(256) void castx_kernel(
    const float* __restrict__ in, _Float16* __restrict__ out) {
  const int gid = blockIdx.x * 256 + threadIdx.x;   // one float4 each
  const float4 v = ((const float4*)in)[gid];
  f16x4 h;
  h.x = (_Float16)v.x; h.y = (_Float16)v.y;
  h.z = (_Float16)v.z; h.w = (_Float16)v.w;
  *(f16x4*)(out + (size_t)gid * 4) = h;
}

// ---------------- enorm (fp64-exact) + cast E: fp32 -> fp16 ----------------
__global__ __launch_bounds__(256) void enorm_cast_kernel(
    const float* __restrict__ ew, float* __restrict__ enorm,
    _Float16* __restrict__ E16) {
  const int lane = threadIdx.x & 63;
  const int wid  = threadIdx.x >> 6;
  const int row  = blockIdx.x * 4 + wid;
  const float4 v0 = *(const float4*)(ew + (size_t)row * DIM + lane * 8);
  const float4 v1 = *(const float4*)(ew + (size_t)row * DIM + lane * 8 + 4);
  const float f[8] = {v0.x, v0.y, v0.z, v0.w, v1.x, v1.y, v1.z, v1.w};
  f16x8 h;
  double s = 0.0;
#pragma unroll
  for (int k = 0; k < 8; ++k) {
    s = fma((double)f[k], (double)f[k], s);
    h[k] = (_Float16)f[k];
  }
  *(f16x8*)(E16 + (size_t)row * DIM + lane * 8) = h;
#pragma unroll
  for (int off = 32; off > 0; off >>= 1) s += __shfl_down(s, off, 64);
  if (lane == 0) enorm[row] = (float)s;
}

// ---------------- main: fp16 K=512 GEMM + per-chunk top-2 ----------------
// Block tile 128x256 (one chunk), 4 waves, wave tile 64x128, 3-deep pipeline.
// Candidates packed u32: (fmono(score) & 0xFFFFFF00) | code8; chunk id is
// blockIdx.x. Top-2 via sorted min/max network, xor1 single-shuffle merge,
// 16 u32x2 slots/row (disjoint wave halves), scan -> u32 buf1/buf2.
__global__ __launch_bounds__(256, 2) void gemm_top2_kernel(
    const _Float16* __restrict__ X16,   // N x 512
    const _Float16* __restrict__ E16,   // K x 512
    const float* __restrict__ enorm,
    unsigned int* __restrict__ buf1,    // [token][32] packed top-1
    unsigned int* __restrict__ buf2) {  // [token][32] packed top-2
  __shared__ __align__(16) union {
    _Float16 buf[3][12288];           // per phase: A bytes 0..8K, B 8K..24K
    unsigned int mg[BM][16][2];       // 16KB merge (aliases buf[0])
  } sh;

  const int tid  = threadIdx.x;
  const int lane = tid & 63;
  const int wid  = tid >> 6;
  const int quad = lane >> 4;
  const int l15  = lane & 15;

  const int row0  = blockIdx.y * BM;
  const int nbase = blockIdx.x * BN;

  const int wm = (wid >> 1) * 64;    // 0 or 64  (rows)
  const int wn = (wid & 1) * 128;    // 0 or 128 (codes)

  // staging: 24 issues of 1KB (16 rows x 64B). Per wave: A issues wid*2+q
  // (q<2), B issues wid*4+q (q<4). lane -> row lane>>2, phys slot lane&3,
  // fetched chunk (lane&3)^((lane>>3)&3) (baseline-verified map; LDS dest
  // base wave-uniform as required). Two persistent pointers, derived offsets.
  const int srow   = lane >> 2;
  const int schunk = (lane & 3) ^ ((lane >> 3) & 3);

  const int ia0 = wid * 2, ib0 = wid * 4;
  const _Float16* pA = X16 + (size_t)(row0 + ia0 * 16 + srow) * DIM + schunk * 8;
  const _Float16* pB = E16 + (size_t)(nbase + ib0 * 16 + srow) * DIM + schunk * 8;

  auto STAGE = [&](int p) {
    char* base = (char*)(&sh.buf[p][0]);
    async16(pA,            base + ia0 * 1024);
    async16(pA + 16 * DIM, base + ia0 * 1024 + 1024);
    async16(pB,            base + 8192 + ib0 * 1024);
    async16(pB + 16 * DIM, base + 8192 + ib0 * 1024 + 1024);
    async16(pB + 32 * DIM, base + 8192 + ib0 * 1024 + 2048);
    async16(pB + 48 * DIM, base + 8192 + ib0 * 1024 + 3072);
    pA += BK; pB += BK;
  };

  f32x4 acc[4][8];
#pragma unroll
  for (int i = 0; i < 4; ++i)
#pragma unroll
    for (int j = 0; j < 8; ++j) acc[i][j] = (f32x4){0.f, 0.f, 0.f, 0.f};

  // ---- 3-deep pipeline ----
  // Invariant at iter ks top: own outstanding loads = tile ks (6) + tile
  // ks+1 (6, if staged). vmcnt(6) completes the OLDEST 6 (tile ks, FIFO);
  // final iter uses vmcnt(0). s_barrier: all waves' tile-ks loads landed AND
  // all waves finished compute(ks-1) (program order) -> STAGE(ks+2) may
  // overwrite buf[(ks-1)%3]. Within the iter: fragment ds_reads issue FIRST
  // (enter LDS queue ahead), STAGE's VMEM issues overlap MFMA block 1.
  STAGE(0); STAGE(1);
  int pc = 0;
  for (int ks = 0; ks < NK; ++ks) {
    if (ks < NK - 1) {
      asm volatile("s_waitcnt vmcnt(6)" ::: "memory");
    } else {
      asm volatile("s_waitcnt vmcnt(0)" ::: "memory");
    }
    __builtin_amdgcn_sched_barrier(0);
    __builtin_amdgcn_s_barrier();
    __builtin_amdgcn_sched_barrier(0);

    const char* baseA = (const char*)(&sh.buf[pc][0]);
    const char* baseB = baseA + 8192;
    f16x8 a[4], b[4];
#pragma unroll
    for (int i = 0; i < 4; ++i) {
      const int ra = wm + i * 16 + l15;
      a[i] = *(const f16x8*)(baseA + ra * 64 + ((quad ^ ((ra >> 1) & 3)) * 16));
    }
#pragma unroll
    for (int jj = 0; jj < 4; ++jj) {
      const int rb = wn + jj * 16 + l15;
      b[jj] = *(const f16x8*)(baseB + rb * 64 + ((quad ^ ((rb >> 1) & 3)) * 16));
    }
    if (ks + 2 < NK) {
      const int pn = (pc + 2 >= 3) ? pc - 1 : pc + 2;
      STAGE(pn);
    }
    __builtin_amdgcn_s_setprio(1);
#pragma unroll
    for (int i = 0; i < 4; ++i)
#pragma unroll
      for (int jj = 0; jj < 4; ++jj)
        acc[i][jj] = __builtin_amdgcn_mfma_f32_16x16x32_f16(
            a[i], b[jj], acc[i][jj], 0, 0, 0);
    __builtin_amdgcn_s_setprio(0);
    f16x8 b2[4];
#pragma unroll
    for (int jj = 0; jj < 4; ++jj) {
      const int rb = wn + (4 + jj) * 16 + l15;
      b2[jj] = *(const f16x8*)(baseB + rb * 64 + ((quad ^ ((rb >> 1) & 3)) * 16));
    }
    __builtin_amdgcn_s_setprio(1);
#pragma unroll
    for (int i = 0; i < 4; ++i)
#pragma unroll
      for (int jj = 0; jj < 4; ++jj)
        acc[i][4 + jj] = __builtin_amdgcn_mfma_f32_16x16x32_f16(
            a[i], b2[jj], acc[i][4 + jj], 0, 0, 0);
    __builtin_amdgcn_s_setprio(0);

    pc = (pc + 1 >= 3) ? 0 : pc + 1;
  }
  __syncthreads();   // all waves done reading buf before mg (union) writes

  // ---- epilogue (atomic-free, branch-free u32 network) ----
  float en8[8];
#pragma unroll
  for (int j = 0; j < 8; ++j) en8[j] = enorm[nbase + wn + j * 16 + l15];
  const unsigned int cb = (unsigned int)(wn + l15);   // in-chunk code base, 8-bit

#pragma unroll
  for (int i = 0; i < 4; ++i) {
    const int mrow = wm + i * 16 + quad * 4;
#pragma unroll
    for (int r = 0; r < 4; ++r) {
      unsigned int c[8];
#pragma unroll
      for (int j = 0; j < 8; ++j) {
        const float v = fmaf(-2.f, acc[i][j][r], en8[j]);
        c[j] = (fmono(v) & 0xFFFFFF00u) | (cb + j * 16);
      }
      // sorted-pair leaves
      const unsigned int l0 = umin32(c[0], c[1]), h0 = umax32(c[0], c[1]);
      const unsigned int l1 = umin32(c[2], c[3]), h1 = umax32(c[2], c[3]);
      const unsigned int l2 = umin32(c[4], c[5]), h2 = umax32(c[4], c[5]);
      const unsigned int l3 = umin32(c[6], c[7]), h3 = umax32(c[6], c[7]);
      // merge pairs (sorted-pair merge over disjoint sets)
      const unsigned int L0 = umin32(l0, l1);
      const unsigned int S0 = umin32(umax32(l0, l1), umin32(h0, h1));
      const unsigned int L1 = umin32(l2, l3);
      const unsigned int S1 = umin32(umax32(l2, l3), umin32(h2, h3));
      unsigned int p1 = umin32(L0, L1);
      unsigned int p2 = umin32(umax32(L0, L1), umin32(S0, S1));
      // xor1 cross-lane merge (single 32-bit shuffles)
      {
        const unsigned int q1 = (unsigned int)__shfl_xor((int)p1, 1, 64);
        const unsigned int q2 = (unsigned int)__shfl_xor((int)p2, 1, 64);
        const unsigned int hi = umax32(p1, q1);
        p1 = umin32(p1, q1);
        p2 = umin32(hi, umin32(p2, q2));
      }
      if (!(lane & 1)) {
        const int row = mrow + r;
        uint2 w; w.x = p1; w.y = p2;
        // 16 writers/row across 2 waves -> 16 distinct slots (disjoint
        // halves by wid&1; ^(row&7) touches bits 0-2 only, bijective).
        *(uint2*)&sh.mg[row][((wid & 1) * 8 + (l15 >> 1)) ^ (row & 7)][0] = w;
      }
    }
  }
  __syncthreads();

  if (tid < BM) {
    unsigned int g1 = 0xFFFFFFFFu, g2 = 0xFFFFFFFFu;
#pragma unroll
    for (int s = 0; s < 16; ++s) {
      const uint2 v = *(const uint2*)&sh.mg[tid][s ^ (tid & 7)][0];
      const unsigned int lo = umin32(v.x, g1);
      const unsigned int hi = umax32(v.x, g1);
      g1 = lo;
      g2 = umin32(hi, umin32(v.y, g2));
    }
    buf1[(size_t)(row0 + tid) * NCHUNK + blockIdx.x] = g1;
    buf2[(size_t)(row0 + tid) * NCHUNK + blockIdx.x] = g2;
  }
}

// ---------------- fused: exact fp64 rerank + gather + loss ----------------
// One wave per token. Candidate u32 = (mono24 | code8); global code id =
// chunk*256 + code8, chunk = slot index. Winner row is CACHED IN REGISTERS
// during the loop (each lane keeps its own fragment) -- no re-gather.
__global__ __launch_bounds__(256) void rerank_gather_loss_kernel(
    const float* __restrict__ xs, const float* __restrict__ ew,
    const unsigned int* __restrict__ buf1,
    const unsigned int* __restrict__ buf2,
    float* __restrict__ out, float* __restrict__ loss_part) {
  const int lane = threadIdx.x & 63;
  const int wv = threadIdx.x >> 6;
  const int tok = blockIdx.x * 4 + wv;
  const unsigned int p = (lane < 32)
      ? buf1[(size_t)tok * NCHUNK + lane]
      : buf2[(size_t)tok * NCHUNK + (lane - 32)];
  const float S = finv(p & 0xFFFFFF00u);
  float m = S;
#pragma unroll
  for (int off = 32; off > 0; off >>= 1) m = fminf(m, __shfl_xor(m, off, 64));
  unsigned long long mask = __ballot(S < m + MU);

  const float4 x0 = *(const float4*)(xs + (size_t)tok * DIM + lane * 8);
  const float4 x1 = *(const float4*)(xs + (size_t)tok * DIM + lane * 8 + 4);
  const double xd[8] = {x0.x, x0.y, x0.z, x0.w, x1.x, x1.y, x1.z, x1.w};

  double best = __builtin_inf();
  unsigned int besti = 0xFFFFFFFFu;
  float4 be0 = x0, be1 = x1;   // winner row fragments (always overwritten)
  while (mask) {
    const int src = __ffsll(mask) - 1;
    mask &= mask - 1;
    const unsigned int pp = (unsigned int)__shfl((int)p, src, 64);
    const unsigned int ci = (unsigned int)((src & 31) << 8) | (pp & 0xFFu);
    const float4 e0 = *(const float4*)(ew + (size_t)ci * DIM + lane * 8);
    const float4 e1 = *(const float4*)(ew + (size_t)ci * DIM + lane * 8 + 4);
    const double ed[8] = {e0.x, e0.y, e0.z, e0.w, e1.x, e1.y, e1.z, e1.w};
    double s = 0.0;
#pragma unroll
    for (int k = 0; k < 8; ++k) {
      const double d = xd[k] - ed[k];
      s = fma(d, d, s);
    }
#pragma unroll
    for (int off = 32; off > 0; off >>= 1) s += __shfl_xor(s, off, 64);
    if (s < best || (s == best && ci < besti)) {
      best = s; besti = ci; be0 = e0; be1 = e1;
    }
  }

  // write winner row from registers + loss partial (all lanes agree)
  *(float4*)(out + (size_t)tok * DIM + lane * 8) = be0;
  *(float4*)(out + (size_t)tok * DIM + lane * 8 + 4) = be1;
  const float ef[8] = {be0.x, be0.y, be0.z, be0.w, be1.x, be1.y, be1.z, be1.w};
  const float xf[8] = {x0.x, x0.y, x0.z, x0.w, x1.x, x1.y, x1.z, x1.w};
  float ls = 0.f;
#pragma unroll
  for (int k = 0; k < 8; ++k) {
    const float d = ef[k] - xf[k];
    ls = fmaf(d, d, ls);
  }
#pragma unroll
  for (int off = 32; off > 0; off >>= 1) ls += __shfl_xor(ls, off, 64);
  if (lane == 0) loss_part[tok] = ls;
}

// loss partial reduce: 64 blocks x 256 -> one atomic per block.
__global__ __launch_bounds__(256) void loss_reduce_part(
    const float* __restrict__ part, float* __restrict__ loss_acc) {
  const int t = threadIdx.x;
  float s = part[blockIdx.x * 256 + t];
#pragma unroll
  for (int off = 32; off > 0; off >>= 1) s += __shfl_down(s, off, 64);
  __shared__ float ws4[4];
  if ((t & 63) == 0) ws4[t >> 6] = s;
  __syncthreads();
  if (t == 0) atomicAdd(loss_acc, ws4[0] + ws4[1] + ws4[2] + ws4[3]);
}

__global__ void loss_finalize(const float* __restrict__ loss_acc,
                              float* __restrict__ out, int out_size) {
  if (threadIdx.x == 0 && blockIdx.x == 0)
    out[out_size - 1] = *loss_acc * 1.25f / (float)((size_t)N_TOK * DIM);
}

// ---------------- fallback: exact fp64 brute (known-passing) ----------------
#define TT 16
#define CT 16
#define KH 256
#define XPAD 516
#define EPAD 260
__global__ __launch_bounds__(256) void brute_argmin_kernel(
    const float* __restrict__ xs, const float* __restrict__ ew,
    unsigned int* __restrict__ g_idx) {
  __shared__ __align__(16) float Xs[TT * XPAD];
  __shared__ __align__(16) float Es[CT * EPAD];
  __shared__ double cand_v[256];
  __shared__ unsigned int cand_i[256];
  const int t = threadIdx.x;
  const int tok0 = blockIdx.x * TT;
#pragma unroll
  for (int i = 0; i < 32; ++i) {
    const int idx = i * 256 + t;
    const int row = idx >> 9, col = idx & 511;
    Xs[row * XPAD + col] = xs[(size_t)(tok0 + row) * DIM + col];
  }
  const int tt = t >> 4;
  const int cl = t & 15;
  double bv = __builtin_inf();
  unsigned int bi = 0u;
  for (int c0 = 0; c0 < K_CODES; c0 += CT) {
    double s0 = 0.0, s1 = 0.0, s2 = 0.0, s3 = 0.0;
#pragma unroll
    for (int h = 0; h < 2; ++h) {
      __syncthreads();
#pragma unroll
      for (int i = 0; i < 16; ++i) {
        const int idx = i * 256 + t;
        const int row = idx >> 8, col = idx & 255;
        Es[row * EPAD + col] = ew[(size_t)(c0 + row) * DIM + h * KH + col];
      }
      __syncthreads();
      const float* __restrict__ xr = &Xs[tt * XPAD + h * KH];
      const float* __restrict__ er = &Es[cl * EPAD];
#pragma unroll 8
      for (int d = 0; d < KH; d += 4) {
        const float4 xf = *(const float4*)(xr + d);
        const float4 ef = *(const float4*)(er + d);
        const double a0 = (double)xf.x - (double)ef.x;
        const double a1 = (double)xf.y - (double)ef.y;
        const double a2 = (double)xf.z - (double)ef.z;
        const double a3 = (double)xf.w - (double)ef.w;
        s0 = fma(a0, a0, s0); s1 = fma(a1, a1, s1);
        s2 = fma(a2, a2, s2); s3 = fma(a3, a3, s3);
      }
    }
    const double s = (s0 + s1) + (s2 + s3);
    if (s < bv) { bv = s; bi = (unsigned int)(c0 + cl); }
  }
  cand_v[t] = bv; cand_i[t] = bi;
  __syncthreads();
  if (t < TT) {
    double mv = __builtin_inf();
    unsigned int mi = 0xFFFFFFFFu;
#pragma unroll
    for (int j = 0; j < 16; ++j) {
      const double v = cand_v[t * 16 + j];
      const unsigned int i = cand_i[t * 16 + j];
      if (v < mv || (v == mv && i < mi)) { mv = v; mi = i; }
    }
    g_idx[tok0 + t] = mi;
  }
}

__global__ __launch_bounds__(256) void gather_loss_kernel(
    const float* __restrict__ xs, const float* __restrict__ ew,
    const unsigned int* __restrict__ g_idx,
    float* __restrict__ out, float* __restrict__ loss_acc) {
  const int row = blockIdx.x;
  const int t = threadIdx.x;
  const unsigned int idx = g_idx[row];
  const float2 ev = ((const float2*)(ew + (size_t)idx * DIM))[t];
  const float2 xv = ((const float2*)(xs + (size_t)row * DIM))[t];
  ((float2*)(out + (size_t)row * DIM))[t] = ev;
  const float d0 = ev.x - xv.x;
  const float d1 = ev.y - xv.y;
  float s = fmaf(d0, d0, d1 * d1);
#pragma unroll
  for (int off = 32; off > 0; off >>= 1) s += __shfl_down(s, off, 64);
  __shared__ float wsum[4];
  if ((t & 63) == 0) wsum[t >> 6] = s;
  __syncthreads();
  if (t == 0) atomicAdd(loss_acc, wsum[0] + wsum[1] + wsum[2] + wsum[3]);
}

// ---------------- launch ----------------
extern "C" void kernel_launch(void* const* d_in, const int* in_sizes, int n_in,
                              void* d_out, int out_size, void* d_ws, size_t ws_size,
                              hipStream_t stream) {
  const float* xs = (const float*)d_in[0];
  const float* ew = (const float*)d_in[1];
  if (n_in >= 2 && in_sizes[0] == K_CODES * DIM && in_sizes[1] == N_TOK * DIM) {
    const float* tmp = xs; xs = ew; ew = tmp;
  }
  float* out = (float*)d_out;

  char* w = (char*)d_ws;
  _Float16* X16 = (_Float16*)(w);                                   // 16 MB
  _Float16* E16 = (_Float16*)(w + 16777216);                        // 8 MB
  float* enorm = (float*)(w + 25165824);                            // 32 KB
  unsigned int* buf1 = (unsigned int*)(w + 25198592);               // 2 MB
  unsigned int* buf2 = (unsigned int*)(w + 27295744);               // 2 MB
  float* loss_acc = (float*)(w + 29392896);
  const size_t NEED = 29392960;

  // loss partials overlay the X16 region (dead after gemm; rerank is its
  // stream-ordered writer). Zero extra workspace.
  float* loss_part = (float*)(w);

  if (ws_size < NEED) {   // fallback: proven exact path
    unsigned int* fg_idx = (unsigned int*)d_ws;
    float* floss = (float*)((char*)d_ws + (size_t)N_TOK * 4);
    hipMemsetAsync(floss, 0, 4, stream);
    brute_argmin_kernel<<<N_TOK / TT, 256, 0, stream>>>(xs, ew, fg_idx);
    gather_loss_kernel<<<N_TOK, 256, 0, stream>>>(xs, ew, fg_idx, out, floss);
    loss_finalize<<<1, 64, 0, stream>>>(floss, out, out_size);
    return;
  }

  hipMemsetAsync(loss_acc, 0, 4, stream);

  castx_kernel<<<N_TOK * DIM / 4 / 256, 256, 0, stream>>>(xs, X16);
  enorm_cast_kernel<<<K_CODES / 4, 256, 0, stream>>>(ew, enorm, E16);

  dim3 g2(K_CODES / BN, N_TOK / BM);   // 32 x 128
  gemm_top2_kernel<<<g2, 256, 0, stream>>>(X16, E16, enorm, buf1, buf2);

  rerank_gather_loss_kernel<<<N_TOK / 4, 256, 0, stream>>>(xs, ew, buf1, buf2,
                                                           out, loss_part);
  loss_reduce_part<<<N_TOK / 256, 256, 0, stream>>>(loss_part, loss_acc);
  loss_finalize<<<1, 64, 0, stream>>>(loss_acc, out, out_size);
}

// Round 12
// 259.152 us; speedup vs baseline: 1.2703x; 1.0128x over previous
//
// R12: consolidation. R11 post-mortem: gemm at 875 TF = the 2-barrier-per-K
// structure's documented plateau; 3 polish rounds returned 3-6% each. This
// round: (1) fully unroll k-loop (static pc -> const LDS addrs, less VALU);
// (2) fuse castx+enorm_cast (one launch); (3) fuse loss reduce+finalize into
// one 1-block kernel, drop loss_acc memset. Gemm body else identical to R11.
#include <hip/hip_runtime.h>
#include <stdint.h>

#define N_TOK   16384
#define DIM     512
#define K_CODES 8192
#define BM      128
#define BN      256
#define BK      32
#define NK      (DIM / BK)
#define NCHUNK  32
#define MU      0.25f    // rerank margin; fp16+quant score err << MU

typedef __attribute__((ext_vector_type(8))) _Float16 f16x8;
typedef __attribute__((ext_vector_type(4))) _Float16 f16x4;
typedef __attribute__((ext_vector_type(4))) float f32x4;

__device__ __forceinline__ unsigned int fmono(float f) {
  unsigned int b = __float_as_uint(f);
  unsigned int mask = ((int)b < 0) ? 0xFFFFFFFFu : 0x80000000u;
  return b ^ mask;
}
__device__ __forceinline__ float finv(unsigned int m) {
  return (m & 0x80000000u) ? __uint_as_float(m ^ 0x80000000u)
                           : __uint_as_float(~m);
}
__device__ __forceinline__ void async16(const void* gptr, void* lptr) {
  __builtin_amdgcn_global_load_lds(
      (const __attribute__((address_space(1))) unsigned int*)gptr,
      (__attribute__((address_space(3))) unsigned int*)lptr,
      16, 0, 0);
}
__device__ __forceinline__ unsigned int umin32(unsigned int a, unsigned int b) {
  return a < b ? a : b;
}
__device__ __forceinline__ unsigned int umax32(unsigned int a, unsigned int b) {
  return a < b ? b : a;
}

// ---------------- fused prep: cast X (blocks 0..8191) + enorm/cast E ----------------
__global__ __launch_bounds__(256) void prep_kernel(
    const float* __restrict__ xs, const float* __restrict__ ew,
    _Float16* __restrict__ X16, _Float16* __restrict__ E16,
    float* __restrict__ enorm) {
  const int b = blockIdx.x;
  if (b < (N_TOK * DIM / 4 / 256)) {           // cast X: one float4/thread
    const int gid = b * 256 + threadIdx.x;
    const float4 v = ((const float4*)xs)[gid];
    f16x4 h;
    h.x = (_Float16)v.x; h.y = (_Float16)v.y;
    h.z = (_Float16)v.z; h.w = (_Float16)v.w;
    *(f16x4*)(X16 + (size_t)gid * 4) = h;
  } else {                                      // enorm (fp64-exact) + cast E
    const int eb = b - (N_TOK * DIM / 4 / 256);
    const int lane = threadIdx.x & 63;
    const int wid  = threadIdx.x >> 6;
    const int row  = eb * 4 + wid;
    const float4 v0 = *(const float4*)(ew + (size_t)row * DIM + lane * 8);
    const float4 v1 = *(const float4*)(ew + (size_t)row * DIM + lane * 8 + 4);
    const float f[8] = {v0.x, v0.y, v0.z, v0.w, v1.x, v1.y, v1.z, v1.w};
    f16x8 h;
    double s = 0.0;
#pragma unroll
    for (int k = 0; k < 8; ++k) {
      s = fma((double)f[k], (double)f[k], s);
      h[k] = (_Float16)f[k];
    }
    *(f16x8*)(E16 + (size_t)row * DIM + lane * 8) = h;
#pragma unroll
    for (int off = 32; off > 0; off >>= 1) s += __shfl_down(s, off, 64);
    if (lane == 0) enorm[row] = (float)s;
  }
}

// ---------------- main: fp16 K=512 GEMM + per-chunk top-2 ----------------
// Block tile 128x256 (one chunk), 4 waves, wave tile 64x128, 3-deep pipeline
// (fully unrolled; pc static). Candidates packed u32: (fmono(score) &
// 0xFFFFFF00) | code8; chunk id is blockIdx.x. Top-2 via sorted min/max
// network, xor1 single-shuffle merge, 16 u32x2 slots/row, scan -> buf1/buf2.
__global__ __launch_bounds__(256, 2) void gemm_top2_kernel(
    const _Float16* __restrict__ X16,   // N x 512
    const _Float16* __restrict__ E16,   // K x 512
    const float* __restrict__ enorm,
    unsigned int* __restrict__ buf1,    // [token][32] packed top-1
    unsigned int* __restrict__ buf2) {  // [token][32] packed top-2
  __shared__ __align__(16) union {
    _Float16 buf[3][12288];           // per phase: A bytes 0..8K, B 8K..24K
    unsigned int mg[BM][16][2];       // 16KB merge (aliases buf[0])
  } sh;

  const int tid  = threadIdx.x;
  const int lane = tid & 63;
  const int wid  = tid >> 6;
  const int quad = lane >> 4;
  const int l15  = lane & 15;

  const int row0  = blockIdx.y * BM;
  const int nbase = blockIdx.x * BN;

  const int wm = (wid >> 1) * 64;    // 0 or 64  (rows)
  const int wn = (wid & 1) * 128;    // 0 or 128 (codes)

  // staging: 24 issues of 1KB (16 rows x 64B). Per wave: A issues wid*2+q
  // (q<2), B issues wid*4+q (q<4). lane -> row lane>>2, phys slot lane&3,
  // fetched chunk (lane&3)^((lane>>3)&3) (baseline-verified map; LDS dest
  // base wave-uniform as required). Two persistent pointers, derived offsets.
  const int srow   = lane >> 2;
  const int schunk = (lane & 3) ^ ((lane >> 3) & 3);

  const int ia0 = wid * 2, ib0 = wid * 4;
  const _Float16* pA = X16 + (size_t)(row0 + ia0 * 16 + srow) * DIM + schunk * 8;
  const _Float16* pB = E16 + (size_t)(nbase + ib0 * 16 + srow) * DIM + schunk * 8;

  auto STAGE = [&](int p) {
    char* base = (char*)(&sh.buf[p][0]);
    async16(pA,            base + ia0 * 1024);
    async16(pA + 16 * DIM, base + ia0 * 1024 + 1024);
    async16(pB,            base + 8192 + ib0 * 1024);
    async16(pB + 16 * DIM, base + 8192 + ib0 * 1024 + 1024);
    async16(pB + 32 * DIM, base + 8192 + ib0 * 1024 + 2048);
    async16(pB + 48 * DIM, base + 8192 + ib0 * 1024 + 3072);
    pA += BK; pB += BK;
  };

  f32x4 acc[4][8];
#pragma unroll
  for (int i = 0; i < 4; ++i)
#pragma unroll
    for (int j = 0; j < 8; ++j) acc[i][j] = (f32x4){0.f, 0.f, 0.f, 0.f};

  // ---- 3-deep pipeline, fully unrolled (pc = ks%3 static) ----
  // Invariant at iter ks top: own outstanding = tile ks (6) + tile ks+1
  // (6, if staged). vmcnt(6) completes the OLDEST 6 (tile ks, FIFO); final
  // iter vmcnt(0). s_barrier: all waves' tile-ks loads landed AND all waves
  // finished compute(ks-1) -> STAGE(ks+2) may overwrite buf[(ks-1)%3].
  // Fragment ds_reads issue first; STAGE VMEM overlaps MFMA block 1.
  STAGE(0); STAGE(1);
#pragma unroll
  for (int ks = 0; ks < NK; ++ks) {
    const int pc = ks % 3;
    if (ks < NK - 1) {
      asm volatile("s_waitcnt vmcnt(6)" ::: "memory");
    } else {
      asm volatile("s_waitcnt vmcnt(0)" ::: "memory");
    }
    __builtin_amdgcn_sched_barrier(0);
    __builtin_amdgcn_s_barrier();
    __builtin_amdgcn_sched_barrier(0);

    const char* baseA = (const char*)(&sh.buf[pc][0]);
    const char* baseB = baseA + 8192;
    f16x8 a[4], b[4];
#pragma unroll
    for (int i = 0; i < 4; ++i) {
      const int ra = wm + i * 16 + l15;
      a[i] = *(const f16x8*)(baseA + ra * 64 + ((quad ^ ((ra >> 1) & 3)) * 16));
    }
#pragma unroll
    for (int jj = 0; jj < 4; ++jj) {
      const int rb = wn + jj * 16 + l15;
      b[jj] = *(const f16x8*)(baseB + rb * 64 + ((quad ^ ((rb >> 1) & 3)) * 16));
    }
    if (ks + 2 < NK) STAGE((ks + 2) % 3);
    __builtin_amdgcn_s_setprio(1);
#pragma unroll
    for (int i = 0; i < 4; ++i)
#pragma unroll
      for (int jj = 0; jj < 4; ++jj)
        acc[i][jj] = __builtin_amdgcn_mfma_f32_16x16x32_f16(
            a[i], b[jj], acc[i][jj], 0, 0, 0);
    __builtin_amdgcn_s_setprio(0);
    f16x8 b2[4];
#pragma unroll
    for (int jj = 0; jj < 4; ++jj) {
      const int rb = wn + (4 + jj) * 16 + l15;
      b2[jj] = *(const f16x8*)(baseB + rb * 64 + ((quad ^ ((rb >> 1) & 3)) * 16));
    }
    __builtin_amdgcn_s_setprio(1);
#pragma unroll
    for (int i = 0; i < 4; ++i)
#pragma unroll
      for (int jj = 0; jj < 4; ++jj)
        acc[i][4 + jj] = __builtin_amdgcn_mfma_f32_16x16x32_f16(
            a[i], b2[jj], acc[i][4 + jj], 0, 0, 0);
    __builtin_amdgcn_s_setprio(0);
  }
  __syncthreads();   // all waves done reading buf before mg (union) writes

  // ---- epilogue (atomic-free, branch-free u32 network) ----
  float en8[8];
#pragma unroll
  for (int j = 0; j < 8; ++j) en8[j] = enorm[nbase + wn + j * 16 + l15];
  const unsigned int cb = (unsigned int)(wn + l15);   // in-chunk code base, 8-bit

#pragma unroll
  for (int i = 0; i < 4; ++i) {
    const int mrow = wm + i * 16 + quad * 4;
#pragma unroll
    for (int r = 0; r < 4; ++r) {
      unsigned int c[8];
#pragma unroll
      for (int j = 0; j < 8; ++j) {
        const float v = fmaf(-2.f, acc[i][j][r], en8[j]);
        c[j] = (fmono(v) & 0xFFFFFF00u) | (cb + j * 16);
      }
      // sorted-pair leaves
      const unsigned int l0 = umin32(c[0], c[1]), h0 = umax32(c[0], c[1]);
      const unsigned int l1 = umin32(c[2], c[3]), h1 = umax32(c[2], c[3]);
      const unsigned int l2 = umin32(c[4], c[5]), h2 = umax32(c[4], c[5]);
      const unsigned int l3 = umin32(c[6], c[7]), h3 = umax32(c[6], c[7]);
      // merge pairs (sorted-pair merge over disjoint sets)
      const unsigned int L0 = umin32(l0, l1);
      const unsigned int S0 = umin32(umax32(l0, l1), umin32(h0, h1));
      const unsigned int L1 = umin32(l2, l3);
      const unsigned int S1 = umin32(umax32(l2, l3), umin32(h2, h3));
      unsigned int p1 = umin32(L0, L1);
      unsigned int p2 = umin32(umax32(L0, L1), umin32(S0, S1));
      // xor1 cross-lane merge (single 32-bit shuffles)
      {
        const unsigned int q1 = (unsigned int)__shfl_xor((int)p1, 1, 64);
        const unsigned int q2 = (unsigned int)__shfl_xor((int)p2, 1, 64);
        const unsigned int hi = umax32(p1, q1);
        p1 = umin32(p1, q1);
        p2 = umin32(hi, umin32(p2, q2));
      }
      if (!(lane & 1)) {
        const int row = mrow + r;
        uint2 w; w.x = p1; w.y = p2;
        // 16 writers/row across 2 waves -> 16 distinct slots (disjoint
        // halves by wid&1; ^(row&7) touches bits 0-2 only, bijective).
        *(uint2*)&sh.mg[row][((wid & 1) * 8 + (l15 >> 1)) ^ (row & 7)][0] = w;
      }
    }
  }
  __syncthreads();

  if (tid < BM) {
    unsigned int g1 = 0xFFFFFFFFu, g2 = 0xFFFFFFFFu;
#pragma unroll
    for (int s = 0; s < 16; ++s) {
      const uint2 v = *(const uint2*)&sh.mg[tid][s ^ (tid & 7)][0];
      const unsigned int lo = umin32(v.x, g1);
      const unsigned int hi = umax32(v.x, g1);
      g1 = lo;
      g2 = umin32(hi, umin32(v.y, g2));
    }
    buf1[(size_t)(row0 + tid) * NCHUNK + blockIdx.x] = g1;
    buf2[(size_t)(row0 + tid) * NCHUNK + blockIdx.x] = g2;
  }
}

// ---------------- fused: exact fp64 rerank + gather + loss ----------------
// One wave per token. Candidate u32 = (mono24 | code8); global code id =
// chunk*256 + code8, chunk = slot index. Winner row cached in registers.
__global__ __launch_bounds__(256) void rerank_gather_loss_kernel(
    const float* __restrict__ xs, const float* __restrict__ ew,
    const unsigned int* __restrict__ buf1,
    const unsigned int* __restrict__ buf2,
    float* __restrict__ out, float* __restrict__ loss_part) {
  const int lane = threadIdx.x & 63;
  const int wv = threadIdx.x >> 6;
  const int tok = blockIdx.x * 4 + wv;
  const unsigned int p = (lane < 32)
      ? buf1[(size_t)tok * NCHUNK + lane]
      : buf2[(size_t)tok * NCHUNK + (lane - 32)];
  const float S = finv(p & 0xFFFFFF00u);
  float m = S;
#pragma unroll
  for (int off = 32; off > 0; off >>= 1) m = fminf(m, __shfl_xor(m, off, 64));
  unsigned long long mask = __ballot(S < m + MU);

  const float4 x0 = *(const float4*)(xs + (size_t)tok * DIM + lane * 8);
  const float4 x1 = *(const float4*)(xs + (size_t)tok * DIM + lane * 8 + 4);
  const double xd[8] = {x0.x, x0.y, x0.z, x0.w, x1.x, x1.y, x1.z, x1.w};

  double best = __builtin_inf();
  unsigned int besti = 0xFFFFFFFFu;
  float4 be0 = x0, be1 = x1;   // winner row fragments (always overwritten)
  while (mask) {
    const int src = __ffsll(mask) - 1;
    mask &= mask - 1;
    const unsigned int pp = (unsigned int)__shfl((int)p, src, 64);
    const unsigned int ci = (unsigned int)((src & 31) << 8) | (pp & 0xFFu);
    const float4 e0 = *(const float4*)(ew + (size_t)ci * DIM + lane * 8);
    const float4 e1 = *(const float4*)(ew + (size_t)ci * DIM + lane * 8 + 4);
    const double ed[8] = {e0.x, e0.y, e0.z, e0.w, e1.x, e1.y, e1.z, e1.w};
    double s = 0.0;
#pragma unroll
    for (int k = 0; k < 8; ++k) {
      const double d = xd[k] - ed[k];
      s = fma(d, d, s);
    }
#pragma unroll
    for (int off = 32; off > 0; off >>= 1) s += __shfl_xor(s, off, 64);
    if (s < best || (s == best && ci < besti)) {
      best = s; besti = ci; be0 = e0; be1 = e1;
    }
  }

  // write winner row from registers + loss partial (all lanes agree)
  *(float4*)(out + (size_t)tok * DIM + lane * 8) = be0;
  *(float4*)(out + (size_t)tok * DIM + lane * 8 + 4) = be1;
  const float ef[8] = {be0.x, be0.y, be0.z, be0.w, be1.x, be1.y, be1.z, be1.w};
  const float xf[8] = {x0.x, x0.y, x0.z, x0.w, x1.x, x1.y, x1.z, x1.w};
  float ls = 0.f;
#pragma unroll
  for (int k = 0; k < 8; ++k) {
    const float d = ef[k] - xf[k];
    ls = fmaf(d, d, ls);
  }
#pragma unroll
  for (int off = 32; off > 0; off >>= 1) ls += __shfl_xor(ls, off, 64);
  if (lane == 0) loss_part[tok] = ls;
}

// fused loss finalize: ONE block, 1024 threads, no atomics, no memset.
__global__ __launch_bounds__(1024) void loss_final_kernel(
    const float* __restrict__ part, float* __restrict__ out, int out_size) {
  const int t = threadIdx.x;
  float s = 0.f;
#pragma unroll
  for (int i = 0; i < N_TOK / 1024; ++i) s += part[t + i * 1024];
#pragma unroll
  for (int off = 32; off > 0; off >>= 1) s += __shfl_down(s, off, 64);
  __shared__ float ws[16];
  if ((t & 63) == 0) ws[t >> 6] = s;
  __syncthreads();
  if (t < 64) {
    float v = (t < 16) ? ws[t] : 0.f;
#pragma unroll
    for (int off = 8; off > 0; off >>= 1) v += __shfl_down(v, off, 64);
    if (t == 0)
      out[out_size - 1] = v * 1.25f / (float)((size_t)N_TOK * DIM);
  }
}

__global__ void loss_finalize(const float* __restrict__ loss_acc,
                              float* __restrict__ out, int out_size) {
  if (threadIdx.x == 0 && blockIdx.x == 0)
    out[out_size - 1] = *loss_acc * 1.25f / (float)((size_t)N_TOK * DIM);
}

// ---------------- fallback: exact fp64 brute (known-passing) ----------------
#define TT 16
#define CT 16
#define KH 256
#define XPAD 516
#define EPAD 260
__global__ __launch_bounds__(256) void brute_argmin_kernel(
    const float* __restrict__ xs, const float* __restrict__ ew,
    unsigned int* __restrict__ g_idx) {
  __shared__ __align__(16) float Xs[TT * XPAD];
  __shared__ __align__(16) float Es[CT * EPAD];
  __shared__ double cand_v[256];
  __shared__ unsigned int cand_i[256];
  const int t = threadIdx.x;
  const int tok0 = blockIdx.x * TT;
#pragma unroll
  for (int i = 0; i < 32; ++i) {
    const int idx = i * 256 + t;
    const int row = idx >> 9, col = idx & 511;
    Xs[row * XPAD + col] = xs[(size_t)(tok0 + row) * DIM + col];
  }
  const int tt = t >> 4;
  const int cl = t & 15;
  double bv = __builtin_inf();
  unsigned int bi = 0u;
  for (int c0 = 0; c0 < K_CODES; c0 += CT) {
    double s0 = 0.0, s1 = 0.0, s2 = 0.0, s3 = 0.0;
#pragma unroll
    for (int h = 0; h < 2; ++h) {
      __syncthreads();
#pragma unroll
      for (int i = 0; i < 16; ++i) {
        const int idx = i * 256 + t;
        const int row = idx >> 8, col = idx & 255;
        Es[row * EPAD + col] = ew[(size_t)(c0 + row) * DIM + h * KH + col];
      }
      __syncthreads();
      const float* __restrict__ xr = &Xs[tt * XPAD + h * KH];
      const float* __restrict__ er = &Es[cl * EPAD];
#pragma unroll 8
      for (int d = 0; d < KH; d += 4) {
        const float4 xf = *(const float4*)(xr + d);
        const float4 ef = *(const float4*)(er + d);
        const double a0 = (double)xf.x - (double)ef.x;
        const double a1 = (double)xf.y - (double)ef.y;
        const double a2 = (double)xf.z - (double)ef.z;
        const double a3 = (double)xf.w - (double)ef.w;
        s0 = fma(a0, a0, s0); s1 = fma(a1, a1, s1);
        s2 = fma(a2, a2, s2); s3 = fma(a3, a3, s3);
      }
    }
    const double s = (s0 + s1) + (s2 + s3);
    if (s < bv) { bv = s; bi = (unsigned int)(c0 + cl); }
  }
  cand_v[t] = bv; cand_i[t] = bi;
  __syncthreads();
  if (t < TT) {
    double mv = __builtin_inf();
    unsigned int mi = 0xFFFFFFFFu;
#pragma unroll
    for (int j = 0; j < 16; ++j) {
      const double v = cand_v[t * 16 + j];
      const unsigned int i = cand_i[t * 16 + j];
      if (v < mv || (v == mv && i < mi)) { mv = v; mi = i; }
    }
    g_idx[tok0 + t] = mi;
  }
}

__global__ __launch_bounds__(256) void gather_loss_kernel(
    const float* __restrict__ xs, const float* __restrict__ ew,
    const unsigned int* __restrict__ g_idx,
    float* __restrict__ out, float* __restrict__ loss_acc) {
  const int row = blockIdx.x;
  const int t = threadIdx.x;
  const unsigned int idx = g_idx[row];
  const float2 ev = ((const float2*)(ew + (size_t)idx * DIM))[t];
  const float2 xv = ((const float2*)(xs + (size_t)row * DIM))[t];
  ((float2*)(out + (size_t)row * DIM))[t] = ev;
  const float d0 = ev.x - xv.x;
  const float d1 = ev.y - xv.y;
  float s = fmaf(d0, d0, d1 * d1);
#pragma unroll
  for (int off = 32; off > 0; off >>= 1) s += __shfl_down(s, off, 64);
  __shared__ float wsum[4];
  if ((t & 63) == 0) wsum[t >> 6] = s;
  __syncthreads();
  if (t == 0) atomicAdd(loss_acc, wsum[0] + wsum[1] + wsum[2] + wsum[3]);
}

// ---------------- launch ----------------
extern "C" void kernel_launch(void* const* d_in, const int* in_sizes, int n_in,
                              void* d_out, int out_size, void* d_ws, size_t ws_size,
                              hipStream_t stream) {
  const float* xs = (const float*)d_in[0];
  const float* ew = (const float*)d_in[1];
  if (n_in >= 2 && in_sizes[0] == K_CODES * DIM && in_sizes[1] == N_TOK * DIM) {
    const float* tmp = xs; xs = ew; ew = tmp;
  }
  float* out = (float*)d_out;

  char* w = (char*)d_ws;
  _Float16* X16 = (_Float16*)(w);                                   // 16 MB
  _Float16* E16 = (_Float16*)(w + 16777216);                        // 8 MB
  float* enorm = (float*)(w + 25165824);                            // 32 KB
  unsigned int* buf1 = (unsigned int*)(w + 25198592);               // 2 MB
  unsigned int* buf2 = (unsigned int*)(w + 27295744);               // 2 MB
  const size_t NEED = 29392960;

  // loss partials overlay the X16 region (dead after gemm; rerank is its
  // stream-ordered writer). Zero extra workspace.
  float* loss_part = (float*)(w);

  if (ws_size < NEED) {   // fallback: proven exact path
    unsigned int* fg_idx = (unsigned int*)d_ws;
    float* floss = (float*)((char*)d_ws + (size_t)N_TOK * 4);
    hipMemsetAsync(floss, 0, 4, stream);
    brute_argmin_kernel<<<N_TOK / TT, 256, 0, stream>>>(xs, ew, fg_idx);
    gather_loss_kernel<<<N_TOK, 256, 0, stream>>>(xs, ew, fg_idx, out, floss);
    loss_finalize<<<1, 64, 0, stream>>>(floss, out, out_size);
    return;
  }

  prep_kernel<<<N_TOK * DIM / 4 / 256 + K_CODES / 4, 256, 0, stream>>>(
      xs, ew, X16, E16, enorm);

  dim3 g2(K_CODES / BN, N_TOK / BM);   // 32 x 128
  gemm_top2_kernel<<<g2, 256, 0, stream>>>(X16, E16, enorm, buf1, buf2);

  rerank_gather_loss_kernel<<<N_TOK / 4, 256, 0, stream>>>(xs, ew, buf1, buf2,
                                                           out, loss_part);
  loss_final_kernel<<<1, 1024, 0, stream>>>(loss_part, out, out_size);
}